// Round 6
// baseline (630.798 us; speedup 1.0000x reference)
//
#include <hip/hip_runtime.h>
#include <hip/hip_bf16.h>
#include <math.h>

#define N_NODES 50000
#define N_EDGES 800000
#define M_EDGES (N_EDGES + N_NODES)
#define NGRAPH 512
#define CH1 128
#define CH2 64

typedef __attribute__((ext_vector_type(8))) short bfrag8;
typedef __attribute__((ext_vector_type(4))) float floatx4;

__device__ __forceinline__ float wave_max(float v){
  #pragma unroll
  for (int o = 32; o; o >>= 1) v = fmaxf(v, __shfl_xor(v, o));
  return v;
}
__device__ __forceinline__ float wave_sum(float v){
  #pragma unroll
  for (int o = 32; o; o >>= 1) v += __shfl_xor(v, o);
  return v;
}
__device__ __forceinline__ unsigned short f2bf(float f){
  union { float f; unsigned int u; } v; v.f = f;
  unsigned int r = v.u + 0x7FFFu + ((v.u >> 16) & 1u);
  return (unsigned short)(r >> 16);
}
__device__ __forceinline__ float bf2f(unsigned short h){
  union { unsigned int u; float f; } v; v.u = ((unsigned int)h) << 16; return v.f;
}

// ---------------- CSR build (dst-major, includes self loops) ----------------
__global__ void k_count(const int* __restrict__ ei, int* __restrict__ deg){
  int e = blockIdx.x * blockDim.x + threadIdx.x;
  if (e >= M_EDGES) return;
  int dst = (e < N_EDGES) ? ei[N_EDGES + e] : (e - N_EDGES);
  atomicAdd(&deg[dst], 1);
}
__global__ void k_alloc(const int* __restrict__ deg, int* __restrict__ row_start,
                        int* __restrict__ cursor){
  int n = blockIdx.x * blockDim.x + threadIdx.x;
  if (n >= N_NODES) return;
  row_start[n] = atomicAdd(cursor, deg[n]);
}
__global__ void k_fill(const int* __restrict__ ei, const int* __restrict__ row_start,
                       int* __restrict__ fill, int* __restrict__ col){
  int e = blockIdx.x * blockDim.x + threadIdx.x;
  if (e >= M_EDGES) return;
  int src, dst;
  if (e < N_EDGES){ src = ei[e]; dst = ei[N_EDGES + e]; }
  else { src = dst = e - N_EDGES; }
  int slot = row_start[dst] + atomicAdd(&fill[dst], 1);
  col[slot] = src;
}

// ------------- split x rows into [N][512] bf16 (hi | lo panels) -------------
__global__ __launch_bounds__(256) void k_splitx(const float* __restrict__ x,
                                                unsigned short* __restrict__ x2){
  const int n = blockIdx.x, tid = threadIdx.x;
  float v = x[(size_t)n * 256 + tid];
  unsigned short hi = f2bf(v);
  x2[(size_t)n * 512 + tid] = hi;
  x2[(size_t)n * 512 + 256 + tid] = f2bf(v - bf2f(hi));
}

// ------- P projection: P[k][0..3]=W1*a_src per head, [4..7]=W1*a_dst --------
__global__ __launch_bounds__(256) void k_projP(const float* __restrict__ W1,
                                               const float* __restrict__ as1,
                                               const float* __restrict__ ad1,
                                               float* __restrict__ P){
  int k = threadIdx.x;
  float acc[8] = {0.f,0.f,0.f,0.f,0.f,0.f,0.f,0.f};
  for (int c = 0; c < 64; ++c){
    #pragma unroll
    for (int h = 0; h < 4; ++h){
      float w = W1[k * 256 + h * 64 + c];
      acc[h]     += w * as1[h * 64 + c];
      acc[4 + h] += w * ad1[h * 64 + c];
    }
  }
  #pragma unroll
  for (int j = 0; j < 8; ++j) P[k * 8 + j] = acc[j];
}

// ---------- attention scalars via projection: asrc/adst = x @ P -------------
__global__ __launch_bounds__(256) void k_att1p(const float* __restrict__ x,
                                               const float* __restrict__ P,
                                               float* __restrict__ asrc,
                                               float* __restrict__ adst){
  __shared__ float Ps[256][9];
  const int tid = threadIdx.x;
  #pragma unroll
  for (int j = 0; j < 8; ++j) Ps[tid][j] = P[tid * 8 + j];
  __syncthreads();
  const int n = blockIdx.x * 4 + (tid >> 6);
  const int lane = tid & 63;
  float4 xv = *(const float4*)&x[(size_t)n * 256 + lane * 4];
  float p[8];
  #pragma unroll
  for (int j = 0; j < 8; ++j){
    p[j] = xv.x * Ps[lane * 4 + 0][j] + xv.y * Ps[lane * 4 + 1][j]
         + xv.z * Ps[lane * 4 + 2][j] + xv.w * Ps[lane * 4 + 3][j];
    p[j] = wave_sum(p[j]);
  }
  if (lane == 0){
    *(float4*)&asrc[n * 4] = make_float4(p[0], p[1], p[2], p[3]);
    *(float4*)&adst[n * 4] = make_float4(p[4], p[5], p[6], p[7]);
  }
}

// ------ split weights into B^T panels: Bt[n][k]: [hi | hi | lo] x 256 -------
// W is [256][Ncols] row-major.
__global__ void k_splitW(const float* __restrict__ W, unsigned short* __restrict__ Bt,
                         int Ncols){
  int n = blockIdx.x, k = threadIdx.x;   // 768 threads
  float w = W[(size_t)(k & 255) * Ncols + n];
  unsigned short hi = f2bf(w);
  Bt[(size_t)n * 768 + k] = (k < 512) ? hi : f2bf(w - bf2f(hi));
}

// ------------- split-bf16 MFMA GEMM: C = A2(panels) @ Bt^T ------------------
// A [M][512] bf16 (hi cols 0-255, lo 256-511), Bt [N][768] bf16.
// Logical K=768 (hi*hi + lo*hi + hi*lo); A panel col = kc & 511.
// BM=128 BN=64 BK=64, 4 waves (2x2). C written fp32 [M][ldc].
__global__ __launch_bounds__(256) void mfma_gemm(const unsigned short* __restrict__ A,
                                                 const unsigned short* __restrict__ Bt,
                                                 float* __restrict__ C,
                                                 int M, int ldc){
  __shared__ unsigned short As[128 * 64];
  __shared__ unsigned short Bs[64 * 64];
  const int tid = threadIdx.x;
  const int m0 = blockIdx.y * 128, n0 = blockIdx.x * 64;
  floatx4 acc[4][2];
  #pragma unroll
  for (int mr = 0; mr < 4; ++mr)
    #pragma unroll
    for (int nr = 0; nr < 2; ++nr) acc[mr][nr] = (floatx4){0.f, 0.f, 0.f, 0.f};
  const int l = tid & 63, w = tid >> 6;
  const int wm = (w >> 1) * 64, wn = (w & 1) * 32;
  const int lr = l & 15, lk = (l >> 4) * 8;

  for (int kc = 0; kc < 768; kc += 64){
    #pragma unroll
    for (int i = 0; i < 4; ++i){
      int f = tid + i * 256, row = f >> 3, seg = f & 7;
      float4 v = make_float4(0.f, 0.f, 0.f, 0.f);
      if (m0 + row < M)
        v = *(const float4*)&A[(size_t)(m0 + row) * 512 + (kc & 511) + seg * 8];
      *(float4*)&As[row * 64 + seg * 8] = v;
    }
    #pragma unroll
    for (int i = 0; i < 2; ++i){
      int f = tid + i * 256, row = f >> 3, seg = f & 7;
      *(float4*)&Bs[row * 64 + seg * 8] =
        *(const float4*)&Bt[(size_t)(n0 + row) * 768 + kc + seg * 8];
    }
    __syncthreads();
    #pragma unroll
    for (int kk = 0; kk < 2; ++kk){
      bfrag8 b0 = *(const bfrag8*)&Bs[(wn + lr) * 64 + kk * 32 + lk];
      bfrag8 b1v = *(const bfrag8*)&Bs[(wn + 16 + lr) * 64 + kk * 32 + lk];
      #pragma unroll
      for (int mr = 0; mr < 4; ++mr){
        bfrag8 a = *(const bfrag8*)&As[(wm + mr * 16 + lr) * 64 + kk * 32 + lk];
        acc[mr][0] = __builtin_amdgcn_mfma_f32_16x16x32_bf16(a, b0, acc[mr][0], 0, 0, 0);
        acc[mr][1] = __builtin_amdgcn_mfma_f32_16x16x32_bf16(a, b1v, acc[mr][1], 0, 0, 0);
      }
    }
    __syncthreads();
  }
  #pragma unroll
  for (int mr = 0; mr < 4; ++mr)
    #pragma unroll
    for (int nr = 0; nr < 2; ++nr){
      const int colg = n0 + wn + nr * 16 + lr;
      #pragma unroll
      for (int r = 0; r < 4; ++r){
        const int row = m0 + wm + mr * 16 + (l >> 4) * 4 + r;
        if (row < M) C[(size_t)row * ldc + colg] = acc[mr][nr][r];
      }
    }
}

// -------- conv1 aggregate of h1 rows, +b1, ELU, split-bf16 out --------------
__global__ __launch_bounds__(256) void k_agg1(const float* __restrict__ h1,
                                              const int* __restrict__ col,
                                              const int* __restrict__ row_start,
                                              const int* __restrict__ degv,
                                              const float* __restrict__ asrc,
                                              const float* __restrict__ adst,
                                              const float* __restrict__ b1,
                                              unsigned short* __restrict__ out1s){
  __shared__ int    src_s[CH1];
  __shared__ float4 w4_s[CH1];
  __shared__ float  redm[4][4];
  __shared__ float  reds[4][4];
  __shared__ float  mh4[4], sh4[4];
  __shared__ float4 racc[4][64];
  const int n = blockIdx.x, tid = threadIdx.x;
  const int wv = tid >> 6, lane = tid & 63;
  const int base = row_start[n], dg = degv[n];
  const float4 ad4 = *(const float4*)&adst[(size_t)n * 4];

  // phase 1: per-head max over edges
  float lm0 = -3e38f, lm1 = -3e38f, lm2 = -3e38f, lm3 = -3e38f;
  for (int j = tid; j < dg; j += 256){
    const float4 s4 = *(const float4*)&asrc[(size_t)col[base + j] * 4];
    float e0 = s4.x + ad4.x; e0 = e0 > 0.f ? e0 : 0.2f * e0; lm0 = fmaxf(lm0, e0);
    float e1 = s4.y + ad4.y; e1 = e1 > 0.f ? e1 : 0.2f * e1; lm1 = fmaxf(lm1, e1);
    float e2 = s4.z + ad4.z; e2 = e2 > 0.f ? e2 : 0.2f * e2; lm2 = fmaxf(lm2, e2);
    float e3 = s4.w + ad4.w; e3 = e3 > 0.f ? e3 : 0.2f * e3; lm3 = fmaxf(lm3, e3);
  }
  lm0 = wave_max(lm0); lm1 = wave_max(lm1); lm2 = wave_max(lm2); lm3 = wave_max(lm3);
  if (lane == 0){ redm[wv][0] = lm0; redm[wv][1] = lm1; redm[wv][2] = lm2; redm[wv][3] = lm3; }
  __syncthreads();
  if (tid < 4)
    mh4[tid] = fmaxf(fmaxf(redm[0][tid], redm[1][tid]), fmaxf(redm[2][tid], redm[3][tid]));
  __syncthreads();
  const float m0 = mh4[0], m1 = mh4[1], m2 = mh4[2], m3 = mh4[3];

  // fused phase 2+3
  float ls0 = 0.f, ls1 = 0.f, ls2 = 0.f, ls3 = 0.f;
  float4 acc = make_float4(0.f, 0.f, 0.f, 0.f);
  const int hsel = lane >> 4;  // head owning channels 4*lane..4*lane+3 of h1
  for (int c0 = 0; c0 < dg; c0 += CH1){
    const int cnt = min(CH1, dg - c0);
    __syncthreads();
    if (tid < cnt){
      const int src = col[base + c0 + tid];
      const float4 s4 = *(const float4*)&asrc[(size_t)src * 4];
      float e0 = s4.x + ad4.x; e0 = e0 > 0.f ? e0 : 0.2f * e0; float w0 = __expf(e0 - m0);
      float e1 = s4.y + ad4.y; e1 = e1 > 0.f ? e1 : 0.2f * e1; float w1 = __expf(e1 - m1);
      float e2 = s4.z + ad4.z; e2 = e2 > 0.f ? e2 : 0.2f * e2; float w2 = __expf(e2 - m2);
      float e3 = s4.w + ad4.w; e3 = e3 > 0.f ? e3 : 0.2f * e3; float w3 = __expf(e3 - m3);
      ls0 += w0; ls1 += w1; ls2 += w2; ls3 += w3;
      src_s[tid] = src;
      w4_s[tid] = make_float4(w0, w1, w2, w3);
    }
    __syncthreads();
    int j = wv;
    for (; j + 4 < cnt; j += 8){
      const float wtA = ((const float*)&w4_s[j])[hsel];
      const float wtB = ((const float*)&w4_s[j + 4])[hsel];
      const float4 hvA = *(const float4*)&h1[(size_t)src_s[j] * 256 + lane * 4];
      const float4 hvB = *(const float4*)&h1[(size_t)src_s[j + 4] * 256 + lane * 4];
      acc.x += wtA * hvA.x; acc.y += wtA * hvA.y; acc.z += wtA * hvA.z; acc.w += wtA * hvA.w;
      acc.x += wtB * hvB.x; acc.y += wtB * hvB.y; acc.z += wtB * hvB.z; acc.w += wtB * hvB.w;
    }
    if (j < cnt){
      const float wt = ((const float*)&w4_s[j])[hsel];
      const float4 hv = *(const float4*)&h1[(size_t)src_s[j] * 256 + lane * 4];
      acc.x += wt * hv.x; acc.y += wt * hv.y; acc.z += wt * hv.z; acc.w += wt * hv.w;
    }
  }
  ls0 = wave_sum(ls0); ls1 = wave_sum(ls1); ls2 = wave_sum(ls2); ls3 = wave_sum(ls3);
  if (lane == 0){ reds[wv][0] = ls0; reds[wv][1] = ls1; reds[wv][2] = ls2; reds[wv][3] = ls3; }
  racc[wv][lane] = acc;
  __syncthreads();
  if (tid < 4) sh4[tid] = reds[0][tid] + reds[1][tid] + reds[2][tid] + reds[3][tid];
  __syncthreads();
  const float inv = 1.f / (sh4[tid >> 6] + 1e-16f);
  const int c4 = tid >> 2, cm = tid & 3;
  float v = ((const float*)&racc[0][c4])[cm] + ((const float*)&racc[1][c4])[cm]
          + ((const float*)&racc[2][c4])[cm] + ((const float*)&racc[3][c4])[cm];
  float o = v * inv + b1[tid];
  o = o > 0.f ? o : __expf(o) - 1.f;
  unsigned short hi = f2bf(o);
  out1s[(size_t)n * 512 + tid] = hi;
  out1s[(size_t)n * 512 + 256 + tid] = f2bf(o - bf2f(hi));
}

// ---------------- conv2 attention scalars (1 head) --------------------------
__global__ __launch_bounds__(64) void k_att2(const float* __restrict__ t2,
                                             const float* __restrict__ a_src,
                                             const float* __restrict__ a_dst,
                                             float* __restrict__ asrc,
                                             float* __restrict__ adst){
  int n = blockIdx.x, lane = threadIdx.x;
  float v = t2[(size_t)n * 64 + lane];
  float ps = wave_sum(v * a_src[lane]);
  float pd = wave_sum(v * a_dst[lane]);
  if (lane == 0){ asrc[n] = ps; adst[n] = pd; }
}

// ------- conv2 aggregate (4 edge-groups x 16 lanes x float4) + b2 + ELU -----
__global__ __launch_bounds__(64) void k_agg2(const float* __restrict__ t2,
                                             const int* __restrict__ col,
                                             const int* __restrict__ row_start,
                                             const int* __restrict__ degv,
                                             const float* __restrict__ asrc,
                                             const float* __restrict__ adst,
                                             const float* __restrict__ b2,
                                             const float* __restrict__ Wg,
                                             const float* __restrict__ bg,
                                             float* __restrict__ hf,
                                             float* __restrict__ attg){
  __shared__ int   src_s[CH2];
  __shared__ float w_s[CH2];
  const int n = blockIdx.x, lane = threadIdx.x;
  const int base = row_start[n], dg = degv[n];
  const float ad = adst[n];
  float lm = -3e38f;
  for (int j = lane; j < dg; j += 64){
    float e = asrc[col[base + j]] + ad;
    e = e > 0.f ? e : 0.2f * e;
    lm = fmaxf(lm, e);
  }
  lm = wave_max(lm);
  float ls = 0.f;
  float4 acc = make_float4(0.f, 0.f, 0.f, 0.f);
  const int eg = lane >> 4, c4 = (lane & 15) * 4;
  for (int c0 = 0; c0 < dg; c0 += CH2){
    const int cnt = min(CH2, dg - c0);
    __syncthreads();
    if (lane < cnt){
      const int src = col[base + c0 + lane];
      float e = asrc[src] + ad;
      e = e > 0.f ? e : 0.2f * e;
      float w = __expf(e - lm);
      ls += w;
      src_s[lane] = src;
      w_s[lane] = w;
    }
    __syncthreads();
    for (int j = eg; j < cnt; j += 4){
      const float wt = w_s[j];
      const float4 tv = *(const float4*)&t2[(size_t)src_s[j] * 64 + c4];
      acc.x += wt * tv.x; acc.y += wt * tv.y; acc.z += wt * tv.z; acc.w += wt * tv.w;
    }
  }
  ls = wave_sum(ls);
  #pragma unroll
  for (int o = 16; o <= 32; o <<= 1){
    acc.x += __shfl_xor(acc.x, o); acc.y += __shfl_xor(acc.y, o);
    acc.z += __shfl_xor(acc.z, o); acc.w += __shfl_xor(acc.w, o);
  }
  const float inv = 1.f / (ls + 1e-16f);
  float o0 = acc.x * inv + b2[c4 + 0]; o0 = o0 > 0.f ? o0 : __expf(o0) - 1.f;
  float o1 = acc.y * inv + b2[c4 + 1]; o1 = o1 > 0.f ? o1 : __expf(o1) - 1.f;
  float o2 = acc.z * inv + b2[c4 + 2]; o2 = o2 > 0.f ? o2 : __expf(o2) - 1.f;
  float o3 = acc.w * inv + b2[c4 + 3]; o3 = o3 > 0.f ? o3 : __expf(o3) - 1.f;
  if (eg == 0) *(float4*)&hf[(size_t)n * 64 + c4] = make_float4(o0, o1, o2, o3);
  float p = (eg == 0)
          ? (o0 * Wg[c4] + o1 * Wg[c4 + 1] + o2 * Wg[c4 + 2] + o3 * Wg[c4 + 3]) : 0.f;
  p = wave_sum(p);
  if (lane == 0) attg[n] = p + bg[0];
}

// --------- per-graph softmax pooling + 2-layer classifier -------------------
__global__ __launch_bounds__(64) void k_pool(const float* __restrict__ hf,
                                             const float* __restrict__ attg,
                                             const int* __restrict__ batch,
                                             const float* __restrict__ Wc1,
                                             const float* __restrict__ bc1,
                                             const float* __restrict__ Wc2,
                                             const float* __restrict__ bc2,
                                             float* __restrict__ out){
  __shared__ float pooled[64];
  __shared__ float hid[32];
  const int g = blockIdx.x, lane = threadIdx.x;
  int lo = 0, hi = N_NODES;
  while (lo < hi){ int mid = (lo + hi) >> 1; if (batch[mid] < g) lo = mid + 1; else hi = mid; }
  const int s0 = lo;
  hi = N_NODES;
  while (lo < hi){ int mid = (lo + hi) >> 1; if (batch[mid] < g + 1) lo = mid + 1; else hi = mid; }
  const int s1 = lo;
  float lm = -3e38f;
  for (int j = s0 + lane; j < s1; j += 64) lm = fmaxf(lm, attg[j]);
  lm = wave_max(lm);
  float ls = 0.f;
  for (int j = s0 + lane; j < s1; j += 64) ls += __expf(attg[j] - lm);
  ls = wave_sum(ls);
  const float inv = 1.f / (ls + 1e-16f);
  float acc = 0.f;
  for (int j = s0; j < s1; ++j)
    acc += __expf(attg[j] - lm) * hf[(size_t)j * 64 + lane];
  pooled[lane] = acc * inv;
  __syncthreads();
  if (lane < 32){
    float t = bc1[lane];
    #pragma unroll
    for (int c = 0; c < 64; ++c) t += pooled[c] * Wc1[c * 32 + lane];
    hid[lane] = t > 0.f ? t : 0.f;
  }
  __syncthreads();
  if (lane < 2){
    float t = bc2[lane];
    #pragma unroll
    for (int c = 0; c < 32; ++c) t += hid[c] * Wc2[c * 2 + lane];
    out[g * 2 + lane] = t;
  }
}

extern "C" void kernel_launch(void* const* d_in, const int* in_sizes, int n_in,
                              void* d_out, int out_size, void* d_ws, size_t ws_size,
                              hipStream_t stream){
  const float* x    = (const float*)d_in[0];
  const int*   ei   = (const int*)d_in[1];
  const int*   batch= (const int*)d_in[2];
  const float* W1   = (const float*)d_in[3];
  const float* as1  = (const float*)d_in[4];
  const float* ad1  = (const float*)d_in[5];
  const float* b1   = (const float*)d_in[6];
  const float* W2   = (const float*)d_in[7];
  const float* as2  = (const float*)d_in[8];
  const float* ad2  = (const float*)d_in[9];
  const float* b2   = (const float*)d_in[10];
  const float* Wg   = (const float*)d_in[11];
  const float* bg   = (const float*)d_in[12];
  const float* Wc1  = (const float*)d_in[13];
  const float* bc1  = (const float*)d_in[14];
  const float* Wc2  = (const float*)d_in[15];
  const float* bc2  = (const float*)d_in[16];

  char* ws = (char*)d_ws;
  unsigned short* x2s   = (unsigned short*)(ws + 0LL);         // [N][512] bf16, later reused as out1s
  unsigned short* out1s = (unsigned short*)(ws + 0LL);         // same region (x2 dead after gemm1)
  float* h1     = (float*)(ws + 51200000LL);    // [N][256] f32 = 51.2MB
  float* t2     = (float*)(ws + 102400000LL);   // 12.8MB
  float* hf     = (float*)(ws + 115200000LL);   // 12.8MB (written late by k_agg2)
  float* P      = (float*)(ws + 115200000LL);   // 8KB (dead before hf written)
  unsigned short* W1B3t = (unsigned short*)(ws + 115208192LL); // 393216B
  unsigned short* W2B3t = (unsigned short*)(ws + 115601408LL); // 98304B
  float* asrc1  = (float*)(ws + 128000000LL);   // 800KB
  float* adst1  = (float*)(ws + 128800000LL);   // 800KB
  float* asrc2  = (float*)(ws + 129600000LL);   // 200KB
  float* adst2  = (float*)(ws + 129800000LL);   // 200KB
  float* attg   = (float*)(ws + 130000000LL);   // 200KB
  int*   deg    = (int*)  (ws + 130200000LL);   // 200KB
  int*   fill   = (int*)  (ws + 130400000LL);   // 200KB
  int*   cursor = (int*)  (ws + 130600000LL);   // 256B
  int*   row_st = (int*)  (ws + 130600256LL);   // 200KB
  int*   col    = (int*)  (ws + 130800256LL);   // 3.4MB
  float* outf   = (float*)d_out;

  hipMemsetAsync(ws + 130200000LL, 0, 400256, stream);

  k_count<<<(M_EDGES + 255) / 256, 256, 0, stream>>>(ei, deg);
  k_alloc<<<(N_NODES + 255) / 256, 256, 0, stream>>>(deg, row_st, cursor);
  k_fill<<<(M_EDGES + 255) / 256, 256, 0, stream>>>(ei, row_st, fill, col);

  k_splitx<<<N_NODES, 256, 0, stream>>>(x, x2s);
  k_projP<<<1, 256, 0, stream>>>(W1, as1, ad1, P);
  k_att1p<<<N_NODES / 4, 256, 0, stream>>>(x, P, asrc1, adst1);
  k_splitW<<<256, 768, 0, stream>>>(W1, W1B3t, 256);
  k_splitW<<<64, 768, 0, stream>>>(W2, W2B3t, 64);

  mfma_gemm<<<dim3(4, 391), 256, 0, stream>>>(x2s, W1B3t, h1, N_NODES, 256);
  k_agg1<<<N_NODES, 256, 0, stream>>>(h1, col, row_st, deg, asrc1, adst1, b1, out1s);

  mfma_gemm<<<dim3(1, 391), 256, 0, stream>>>(out1s, W2B3t, t2, N_NODES, 64);
  k_att2<<<N_NODES, 64, 0, stream>>>(t2, as2, ad2, asrc2, adst2);
  k_agg2<<<N_NODES, 64, 0, stream>>>(t2, col, row_st, deg, asrc2, adst2, b2, Wg, bg, hf, attg);

  k_pool<<<NGRAPH, 64, 0, stream>>>(hf, attg, batch, Wc1, bc1, Wc2, bc2, outf);
}

// Round 7
// 555.847 us; speedup vs baseline: 1.1348x; 1.1348x over previous
//
#include <hip/hip_runtime.h>
#include <hip/hip_bf16.h>
#include <hip/hip_fp16.h>
#include <math.h>

#define N_NODES 50000
#define N_EDGES 800000
#define M_EDGES (N_EDGES + N_NODES)
#define NGRAPH 512
#define CH1 128
#define CH2 64

typedef __attribute__((ext_vector_type(8))) short bfrag8;
typedef __attribute__((ext_vector_type(4))) float floatx4;

__device__ __forceinline__ float wave_max(float v){
  #pragma unroll
  for (int o = 32; o; o >>= 1) v = fmaxf(v, __shfl_xor(v, o));
  return v;
}
__device__ __forceinline__ float wave_sum(float v){
  #pragma unroll
  for (int o = 32; o; o >>= 1) v += __shfl_xor(v, o);
  return v;
}
__device__ __forceinline__ unsigned short f2bf(float f){
  union { float f; unsigned int u; } v; v.f = f;
  unsigned int r = v.u + 0x7FFFu + ((v.u >> 16) & 1u);
  return (unsigned short)(r >> 16);
}
__device__ __forceinline__ float bf2f(unsigned short h){
  union { unsigned int u; float f; } v; v.u = ((unsigned int)h) << 16; return v.f;
}

// ---------------- CSR build (dst-major, includes self loops) ----------------
__global__ void k_count(const int* __restrict__ ei, int* __restrict__ deg){
  int e = blockIdx.x * blockDim.x + threadIdx.x;
  if (e >= M_EDGES) return;
  int dst = (e < N_EDGES) ? ei[N_EDGES + e] : (e - N_EDGES);
  atomicAdd(&deg[dst], 1);
}
__global__ void k_alloc(const int* __restrict__ deg, int* __restrict__ row_start,
                        int* __restrict__ cursor){
  int n = blockIdx.x * blockDim.x + threadIdx.x;
  if (n >= N_NODES) return;
  row_start[n] = atomicAdd(cursor, deg[n]);
}
__global__ void k_fill(const int* __restrict__ ei, const int* __restrict__ row_start,
                       int* __restrict__ fill, int* __restrict__ col){
  int e = blockIdx.x * blockDim.x + threadIdx.x;
  if (e >= M_EDGES) return;
  int src, dst;
  if (e < N_EDGES){ src = ei[e]; dst = ei[N_EDGES + e]; }
  else { src = dst = e - N_EDGES; }
  int slot = row_start[dst] + atomicAdd(&fill[dst], 1);
  col[slot] = src;
}

// ------- P projection: P[k][0..3]=W1*a_src per head, [4..7]=W1*a_dst --------
__global__ __launch_bounds__(256) void k_projP(const float* __restrict__ W1,
                                               const float* __restrict__ as1,
                                               const float* __restrict__ ad1,
                                               float* __restrict__ P){
  int k = threadIdx.x;
  float acc[8] = {0.f,0.f,0.f,0.f,0.f,0.f,0.f,0.f};
  for (int c = 0; c < 64; ++c){
    #pragma unroll
    for (int h = 0; h < 4; ++h){
      float w = W1[k * 256 + h * 64 + c];
      acc[h]     += w * as1[h * 64 + c];
      acc[4 + h] += w * ad1[h * 64 + c];
    }
  }
  #pragma unroll
  for (int j = 0; j < 8; ++j) P[k * 8 + j] = acc[j];
}

// --- attention scalars asrc/adst = x @ P, fused with x -> split-bf16 x2 -----
__global__ __launch_bounds__(256) void k_att1p(const float* __restrict__ x,
                                               const float* __restrict__ P,
                                               float* __restrict__ asrc,
                                               float* __restrict__ adst,
                                               unsigned short* __restrict__ x2){
  __shared__ float Ps[256][9];
  const int tid = threadIdx.x;
  #pragma unroll
  for (int j = 0; j < 8; ++j) Ps[tid][j] = P[tid * 8 + j];
  __syncthreads();
  const int n = blockIdx.x * 4 + (tid >> 6);
  const int lane = tid & 63;
  float4 xv = *(const float4*)&x[(size_t)n * 256 + lane * 4];
  // split write (hi | lo panels)
  ushort4 hi4, lo4;
  hi4.x = f2bf(xv.x); lo4.x = f2bf(xv.x - bf2f(hi4.x));
  hi4.y = f2bf(xv.y); lo4.y = f2bf(xv.y - bf2f(hi4.y));
  hi4.z = f2bf(xv.z); lo4.z = f2bf(xv.z - bf2f(hi4.z));
  hi4.w = f2bf(xv.w); lo4.w = f2bf(xv.w - bf2f(hi4.w));
  *(ushort4*)&x2[(size_t)n * 512 + lane * 4] = hi4;
  *(ushort4*)&x2[(size_t)n * 512 + 256 + lane * 4] = lo4;
  float p[8];
  #pragma unroll
  for (int j = 0; j < 8; ++j){
    p[j] = xv.x * Ps[lane * 4 + 0][j] + xv.y * Ps[lane * 4 + 1][j]
         + xv.z * Ps[lane * 4 + 2][j] + xv.w * Ps[lane * 4 + 3][j];
    p[j] = wave_sum(p[j]);
  }
  if (lane == 0){
    *(float4*)&asrc[n * 4] = make_float4(p[0], p[1], p[2], p[3]);
    *(float4*)&adst[n * 4] = make_float4(p[4], p[5], p[6], p[7]);
  }
}

// ------ split weights into B^T panels: Bt[n][k]: [hi | hi | lo] x 256 -------
__global__ void k_splitW(const float* __restrict__ W, unsigned short* __restrict__ Bt,
                         int Ncols){
  int n = blockIdx.x, k = threadIdx.x;   // 768 threads
  float w = W[(size_t)(k & 255) * Ncols + n];
  unsigned short hi = f2bf(w);
  Bt[(size_t)n * 768 + k] = (k < 512) ? hi : f2bf(w - bf2f(hi));
}

// ------------- split-bf16 MFMA GEMM: C = A2(panels) @ Bt^T ------------------
// A [M][512] bf16 (hi 0-255, lo 256-511), Bt [N][768] bf16 (hi|hi|lo).
// Logical K=768 = hi*hi + lo*hi + hi*lo. BM=128 BN=64 BK=64, 4 waves (2x2).
// LDS XOR-swizzled in 16B segments: seg ^= row&7 (write and read sides) to
// break the 16-way bank conflict of the 128B row stride.
// OUT_HALF=1: C __half [M][ldc]; else fp32.
template<int OUT_HALF>
__global__ __launch_bounds__(256) void mfma_gemm(const unsigned short* __restrict__ A,
                                                 const unsigned short* __restrict__ Bt,
                                                 void* __restrict__ Cout,
                                                 int M, int ldc){
  __shared__ unsigned short As[128 * 64];
  __shared__ unsigned short Bs[64 * 64];
  const int tid = threadIdx.x;
  const int m0 = blockIdx.y * 128, n0 = blockIdx.x * 64;
  floatx4 acc[4][2];
  #pragma unroll
  for (int mr = 0; mr < 4; ++mr)
    #pragma unroll
    for (int nr = 0; nr < 2; ++nr) acc[mr][nr] = (floatx4){0.f, 0.f, 0.f, 0.f};
  const int l = tid & 63, w = tid >> 6;
  const int wm = (w >> 1) * 64, wn = (w & 1) * 32;
  const int lr = l & 15;

  for (int kc = 0; kc < 768; kc += 64){
    #pragma unroll
    for (int i = 0; i < 4; ++i){
      int f = tid + i * 256, row = f >> 3, seg = f & 7;
      int sseg = seg ^ (row & 7);
      float4 v = make_float4(0.f, 0.f, 0.f, 0.f);
      if (m0 + row < M)
        v = *(const float4*)&A[(size_t)(m0 + row) * 512 + (kc & 511) + seg * 8];
      *(float4*)&As[row * 64 + sseg * 8] = v;
    }
    #pragma unroll
    for (int i = 0; i < 2; ++i){
      int f = tid + i * 256, row = f >> 3, seg = f & 7;
      int sseg = seg ^ (row & 7);
      *(float4*)&Bs[row * 64 + sseg * 8] =
        *(const float4*)&Bt[(size_t)(n0 + row) * 768 + kc + seg * 8];
    }
    __syncthreads();
    #pragma unroll
    for (int kk = 0; kk < 2; ++kk){
      const int seg = kk * 4 + (l >> 4);     // 16B segment index 0..7
      const int br0 = wn + lr, br1 = wn + 16 + lr;
      bfrag8 b0  = *(const bfrag8*)&Bs[br0 * 64 + (seg ^ (br0 & 7)) * 8];
      bfrag8 b1v = *(const bfrag8*)&Bs[br1 * 64 + (seg ^ (br1 & 7)) * 8];
      #pragma unroll
      for (int mr = 0; mr < 4; ++mr){
        const int ar = wm + mr * 16 + lr;
        bfrag8 a = *(const bfrag8*)&As[ar * 64 + (seg ^ (ar & 7)) * 8];
        acc[mr][0] = __builtin_amdgcn_mfma_f32_16x16x32_bf16(a, b0, acc[mr][0], 0, 0, 0);
        acc[mr][1] = __builtin_amdgcn_mfma_f32_16x16x32_bf16(a, b1v, acc[mr][1], 0, 0, 0);
      }
    }
    __syncthreads();
  }
  #pragma unroll
  for (int mr = 0; mr < 4; ++mr)
    #pragma unroll
    for (int nr = 0; nr < 2; ++nr){
      const int colg = n0 + wn + nr * 16 + lr;
      #pragma unroll
      for (int r = 0; r < 4; ++r){
        const int row = m0 + wm + mr * 16 + (l >> 4) * 4 + r;
        if (row < M){
          if (OUT_HALF)
            ((__half*)Cout)[(size_t)row * ldc + colg] = __float2half(acc[mr][nr][r]);
          else
            ((float*)Cout)[(size_t)row * ldc + colg] = acc[mr][nr][r];
        }
      }
    }
}

// -------- conv1 aggregate of fp16 h1 rows, +b1, ELU, split-bf16 out ---------
__global__ __launch_bounds__(256) void k_agg1(const __half* __restrict__ h1,
                                              const int* __restrict__ col,
                                              const int* __restrict__ row_start,
                                              const int* __restrict__ degv,
                                              const float* __restrict__ asrc,
                                              const float* __restrict__ adst,
                                              const float* __restrict__ b1,
                                              unsigned short* __restrict__ out1s){
  __shared__ int    src_s[CH1];
  __shared__ float4 w4_s[CH1];
  __shared__ float  redm[4][4];
  __shared__ float  reds[4][4];
  __shared__ float  mh4[4], sh4[4];
  __shared__ float4 racc[4][64];
  const int n = blockIdx.x, tid = threadIdx.x;
  const int wv = tid >> 6, lane = tid & 63;
  const int base = row_start[n], dg = degv[n];
  const float4 ad4 = *(const float4*)&adst[(size_t)n * 4];

  // phase 1: per-head max over edges
  float lm0 = -3e38f, lm1 = -3e38f, lm2 = -3e38f, lm3 = -3e38f;
  for (int j = tid; j < dg; j += 256){
    const float4 s4 = *(const float4*)&asrc[(size_t)col[base + j] * 4];
    float e0 = s4.x + ad4.x; e0 = e0 > 0.f ? e0 : 0.2f * e0; lm0 = fmaxf(lm0, e0);
    float e1 = s4.y + ad4.y; e1 = e1 > 0.f ? e1 : 0.2f * e1; lm1 = fmaxf(lm1, e1);
    float e2 = s4.z + ad4.z; e2 = e2 > 0.f ? e2 : 0.2f * e2; lm2 = fmaxf(lm2, e2);
    float e3 = s4.w + ad4.w; e3 = e3 > 0.f ? e3 : 0.2f * e3; lm3 = fmaxf(lm3, e3);
  }
  lm0 = wave_max(lm0); lm1 = wave_max(lm1); lm2 = wave_max(lm2); lm3 = wave_max(lm3);
  if (lane == 0){ redm[wv][0] = lm0; redm[wv][1] = lm1; redm[wv][2] = lm2; redm[wv][3] = lm3; }
  __syncthreads();
  if (tid < 4)
    mh4[tid] = fmaxf(fmaxf(redm[0][tid], redm[1][tid]), fmaxf(redm[2][tid], redm[3][tid]));
  __syncthreads();
  const float m0 = mh4[0], m1 = mh4[1], m2 = mh4[2], m3 = mh4[3];

  // fused phase 2+3: weights once into LDS, fp16-row gather (8B/lane)
  float ls0 = 0.f, ls1 = 0.f, ls2 = 0.f, ls3 = 0.f;
  float4 acc = make_float4(0.f, 0.f, 0.f, 0.f);
  const int hsel = lane >> 4;
  for (int c0 = 0; c0 < dg; c0 += CH1){
    const int cnt = min(CH1, dg - c0);
    __syncthreads();
    if (tid < cnt){
      const int src = col[base + c0 + tid];
      const float4 s4 = *(const float4*)&asrc[(size_t)src * 4];
      float e0 = s4.x + ad4.x; e0 = e0 > 0.f ? e0 : 0.2f * e0; float w0 = __expf(e0 - m0);
      float e1 = s4.y + ad4.y; e1 = e1 > 0.f ? e1 : 0.2f * e1; float w1 = __expf(e1 - m1);
      float e2 = s4.z + ad4.z; e2 = e2 > 0.f ? e2 : 0.2f * e2; float w2 = __expf(e2 - m2);
      float e3 = s4.w + ad4.w; e3 = e3 > 0.f ? e3 : 0.2f * e3; float w3 = __expf(e3 - m3);
      ls0 += w0; ls1 += w1; ls2 += w2; ls3 += w3;
      src_s[tid] = src;
      w4_s[tid] = make_float4(w0, w1, w2, w3);
    }
    __syncthreads();
    int j = wv;
    for (; j + 12 < cnt; j += 16){
      float wt[4]; uint2 rw[4];
      #pragma unroll
      for (int u = 0; u < 4; ++u){
        wt[u] = ((const float*)&w4_s[j + u * 4])[hsel];
        rw[u] = *(const uint2*)&h1[(size_t)src_s[j + u * 4] * 256 + lane * 4];
      }
      #pragma unroll
      for (int u = 0; u < 4; ++u){
        float2 f01 = __half22float2(*reinterpret_cast<const __half2*>(&rw[u].x));
        float2 f23 = __half22float2(*reinterpret_cast<const __half2*>(&rw[u].y));
        acc.x += wt[u] * f01.x; acc.y += wt[u] * f01.y;
        acc.z += wt[u] * f23.x; acc.w += wt[u] * f23.y;
      }
    }
    for (; j < cnt; j += 4){
      const float wt = ((const float*)&w4_s[j])[hsel];
      const uint2 rw = *(const uint2*)&h1[(size_t)src_s[j] * 256 + lane * 4];
      float2 f01 = __half22float2(*reinterpret_cast<const __half2*>(&rw.x));
      float2 f23 = __half22float2(*reinterpret_cast<const __half2*>(&rw.y));
      acc.x += wt * f01.x; acc.y += wt * f01.y;
      acc.z += wt * f23.x; acc.w += wt * f23.y;
    }
  }
  ls0 = wave_sum(ls0); ls1 = wave_sum(ls1); ls2 = wave_sum(ls2); ls3 = wave_sum(ls3);
  if (lane == 0){ reds[wv][0] = ls0; reds[wv][1] = ls1; reds[wv][2] = ls2; reds[wv][3] = ls3; }
  racc[wv][lane] = acc;
  __syncthreads();
  if (tid < 4) sh4[tid] = reds[0][tid] + reds[1][tid] + reds[2][tid] + reds[3][tid];
  __syncthreads();
  const float inv = 1.f / (sh4[tid >> 6] + 1e-16f);
  const int c4 = tid >> 2, cm = tid & 3;
  float v = ((const float*)&racc[0][c4])[cm] + ((const float*)&racc[1][c4])[cm]
          + ((const float*)&racc[2][c4])[cm] + ((const float*)&racc[3][c4])[cm];
  float o = v * inv + b1[tid];
  o = o > 0.f ? o : __expf(o) - 1.f;
  unsigned short hi = f2bf(o);
  out1s[(size_t)n * 512 + tid] = hi;
  out1s[(size_t)n * 512 + 256 + tid] = f2bf(o - bf2f(hi));
}

// ---------------- conv2 attention scalars (1 head, fp16 t2) -----------------
__global__ __launch_bounds__(64) void k_att2(const __half* __restrict__ t2,
                                             const float* __restrict__ a_src,
                                             const float* __restrict__ a_dst,
                                             float* __restrict__ asrc,
                                             float* __restrict__ adst){
  int n = blockIdx.x, lane = threadIdx.x;
  float v = __half2float(t2[(size_t)n * 64 + lane]);
  float ps = wave_sum(v * a_src[lane]);
  float pd = wave_sum(v * a_dst[lane]);
  if (lane == 0){ asrc[n] = ps; adst[n] = pd; }
}

// ------- conv2 aggregate (4 edge-groups x 16 lanes x 4 halves) + b2 + ELU ---
__global__ __launch_bounds__(64) void k_agg2(const __half* __restrict__ t2,
                                             const int* __restrict__ col,
                                             const int* __restrict__ row_start,
                                             const int* __restrict__ degv,
                                             const float* __restrict__ asrc,
                                             const float* __restrict__ adst,
                                             const float* __restrict__ b2,
                                             const float* __restrict__ Wg,
                                             const float* __restrict__ bg,
                                             float* __restrict__ hf,
                                             float* __restrict__ attg){
  __shared__ int   src_s[CH2];
  __shared__ float w_s[CH2];
  const int n = blockIdx.x, lane = threadIdx.x;
  const int base = row_start[n], dg = degv[n];
  const float ad = adst[n];
  float lm = -3e38f;
  for (int j = lane; j < dg; j += 64){
    float e = asrc[col[base + j]] + ad;
    e = e > 0.f ? e : 0.2f * e;
    lm = fmaxf(lm, e);
  }
  lm = wave_max(lm);
  float ls = 0.f;
  float4 acc = make_float4(0.f, 0.f, 0.f, 0.f);
  const int eg = lane >> 4, c4 = (lane & 15) * 4;
  for (int c0 = 0; c0 < dg; c0 += CH2){
    const int cnt = min(CH2, dg - c0);
    __syncthreads();
    if (lane < cnt){
      const int src = col[base + c0 + lane];
      float e = asrc[src] + ad;
      e = e > 0.f ? e : 0.2f * e;
      float w = __expf(e - lm);
      ls += w;
      src_s[lane] = src;
      w_s[lane] = w;
    }
    __syncthreads();
    for (int j = eg; j < cnt; j += 4){
      const float wt = w_s[j];
      const uint2 rw = *(const uint2*)&t2[(size_t)src_s[j] * 64 + c4];
      float2 f01 = __half22float2(*reinterpret_cast<const __half2*>(&rw.x));
      float2 f23 = __half22float2(*reinterpret_cast<const __half2*>(&rw.y));
      acc.x += wt * f01.x; acc.y += wt * f01.y;
      acc.z += wt * f23.x; acc.w += wt * f23.y;
    }
  }
  ls = wave_sum(ls);
  #pragma unroll
  for (int o = 16; o <= 32; o <<= 1){
    acc.x += __shfl_xor(acc.x, o); acc.y += __shfl_xor(acc.y, o);
    acc.z += __shfl_xor(acc.z, o); acc.w += __shfl_xor(acc.w, o);
  }
  const float inv = 1.f / (ls + 1e-16f);
  float o0 = acc.x * inv + b2[c4 + 0]; o0 = o0 > 0.f ? o0 : __expf(o0) - 1.f;
  float o1 = acc.y * inv + b2[c4 + 1]; o1 = o1 > 0.f ? o1 : __expf(o1) - 1.f;
  float o2 = acc.z * inv + b2[c4 + 2]; o2 = o2 > 0.f ? o2 : __expf(o2) - 1.f;
  float o3 = acc.w * inv + b2[c4 + 3]; o3 = o3 > 0.f ? o3 : __expf(o3) - 1.f;
  if (eg == 0) *(float4*)&hf[(size_t)n * 64 + c4] = make_float4(o0, o1, o2, o3);
  float p = (eg == 0)
          ? (o0 * Wg[c4] + o1 * Wg[c4 + 1] + o2 * Wg[c4 + 2] + o3 * Wg[c4 + 3]) : 0.f;
  p = wave_sum(p);
  if (lane == 0) attg[n] = p + bg[0];
}

// --------- per-graph softmax pooling + 2-layer classifier -------------------
__global__ __launch_bounds__(64) void k_pool(const float* __restrict__ hf,
                                             const float* __restrict__ attg,
                                             const int* __restrict__ batch,
                                             const float* __restrict__ Wc1,
                                             const float* __restrict__ bc1,
                                             const float* __restrict__ Wc2,
                                             const float* __restrict__ bc2,
                                             float* __restrict__ out){
  __shared__ float pooled[64];
  __shared__ float hid[32];
  const int g = blockIdx.x, lane = threadIdx.x;
  int lo = 0, hi = N_NODES;
  while (lo < hi){ int mid = (lo + hi) >> 1; if (batch[mid] < g) lo = mid + 1; else hi = mid; }
  const int s0 = lo;
  hi = N_NODES;
  while (lo < hi){ int mid = (lo + hi) >> 1; if (batch[mid] < g + 1) lo = mid + 1; else hi = mid; }
  const int s1 = lo;
  float lm = -3e38f;
  for (int j = s0 + lane; j < s1; j += 64) lm = fmaxf(lm, attg[j]);
  lm = wave_max(lm);
  float ls = 0.f;
  for (int j = s0 + lane; j < s1; j += 64) ls += __expf(attg[j] - lm);
  ls = wave_sum(ls);
  const float inv = 1.f / (ls + 1e-16f);
  float acc = 0.f;
  for (int j = s0; j < s1; ++j)
    acc += __expf(attg[j] - lm) * hf[(size_t)j * 64 + lane];
  pooled[lane] = acc * inv;
  __syncthreads();
  if (lane < 32){
    float t = bc1[lane];
    #pragma unroll
    for (int c = 0; c < 64; ++c) t += pooled[c] * Wc1[c * 32 + lane];
    hid[lane] = t > 0.f ? t : 0.f;
  }
  __syncthreads();
  if (lane < 2){
    float t = bc2[lane];
    #pragma unroll
    for (int c = 0; c < 32; ++c) t += hid[c] * Wc2[c * 2 + lane];
    out[g * 2 + lane] = t;
  }
}

extern "C" void kernel_launch(void* const* d_in, const int* in_sizes, int n_in,
                              void* d_out, int out_size, void* d_ws, size_t ws_size,
                              hipStream_t stream){
  const float* x    = (const float*)d_in[0];
  const int*   ei   = (const int*)d_in[1];
  const int*   batch= (const int*)d_in[2];
  const float* W1   = (const float*)d_in[3];
  const float* as1  = (const float*)d_in[4];
  const float* ad1  = (const float*)d_in[5];
  const float* b1   = (const float*)d_in[6];
  const float* W2   = (const float*)d_in[7];
  const float* as2  = (const float*)d_in[8];
  const float* ad2  = (const float*)d_in[9];
  const float* b2   = (const float*)d_in[10];
  const float* Wg   = (const float*)d_in[11];
  const float* bg   = (const float*)d_in[12];
  const float* Wc1  = (const float*)d_in[13];
  const float* bc1  = (const float*)d_in[14];
  const float* Wc2  = (const float*)d_in[15];
  const float* bc2  = (const float*)d_in[16];

  char* ws = (char*)d_ws;
  unsigned short* x2s   = (unsigned short*)(ws + 0LL);         // [N][512] bf16 split
  unsigned short* out1s = (unsigned short*)(ws + 0LL);         // same region (x2 dead after gemm1)
  __half* h1h   = (__half*)(ws + 51200000LL);   // [N][256] fp16 = 25.6MB
  __half* t2h   = (__half*)(ws + 102400000LL);  // [N][64] fp16 = 6.4MB
  float* hf     = (float*)(ws + 115200000LL);   // 12.8MB (written late by k_agg2)
  float* P      = (float*)(ws + 115200000LL);   // 8KB (dead before hf written)
  unsigned short* W1B3t = (unsigned short*)(ws + 115208192LL); // 393216B
  unsigned short* W2B3t = (unsigned short*)(ws + 115601408LL); // 98304B
  float* asrc1  = (float*)(ws + 128000000LL);   // 800KB
  float* adst1  = (float*)(ws + 128800000LL);   // 800KB
  float* asrc2  = (float*)(ws + 129600000LL);   // 200KB
  float* adst2  = (float*)(ws + 129800000LL);   // 200KB
  float* attg   = (float*)(ws + 130000000LL);   // 200KB
  int*   deg    = (int*)  (ws + 130200000LL);   // 200KB
  int*   fill   = (int*)  (ws + 130400000LL);   // 200KB
  int*   cursor = (int*)  (ws + 130600000LL);   // 256B
  int*   row_st = (int*)  (ws + 130600256LL);   // 200KB
  int*   col    = (int*)  (ws + 130800256LL);   // 3.4MB
  float* outf   = (float*)d_out;

  hipMemsetAsync(ws + 130200000LL, 0, 400256, stream);

  k_count<<<(M_EDGES + 255) / 256, 256, 0, stream>>>(ei, deg);
  k_alloc<<<(N_NODES + 255) / 256, 256, 0, stream>>>(deg, row_st, cursor);
  k_fill<<<(M_EDGES + 255) / 256, 256, 0, stream>>>(ei, row_st, fill, col);

  k_projP<<<1, 256, 0, stream>>>(W1, as1, ad1, P);
  k_att1p<<<N_NODES / 4, 256, 0, stream>>>(x, P, asrc1, adst1, x2s);
  k_splitW<<<256, 768, 0, stream>>>(W1, W1B3t, 256);
  k_splitW<<<64, 768, 0, stream>>>(W2, W2B3t, 64);

  mfma_gemm<1><<<dim3(4, 391), 256, 0, stream>>>(x2s, W1B3t, (void*)h1h, N_NODES, 256);
  k_agg1<<<N_NODES, 256, 0, stream>>>(h1h, col, row_st, deg, asrc1, adst1, b1, out1s);

  mfma_gemm<1><<<dim3(1, 391), 256, 0, stream>>>(out1s, W2B3t, (void*)t2h, N_NODES, 64);
  k_att2<<<N_NODES, 64, 0, stream>>>(t2h, as2, ad2, asrc2, adst2);
  k_agg2<<<N_NODES, 64, 0, stream>>>(t2h, col, row_st, deg, asrc2, adst2, b2, Wg, bg, hf, attg);

  k_pool<<<NGRAPH, 64, 0, stream>>>(hf, attg, batch, Wc1, bc1, Wc2, bc2, outf);
}

// Round 9
// 508.929 us; speedup vs baseline: 1.2395x; 1.0922x over previous
//
#include <hip/hip_runtime.h>
#include <hip/hip_bf16.h>
#include <hip/hip_fp16.h>
#include <math.h>

#define N_NODES 50000
#define N_EDGES 800000
#define M_EDGES (N_EDGES + N_NODES)
#define NGRAPH 512

typedef __attribute__((ext_vector_type(8))) short bfrag8;
typedef __attribute__((ext_vector_type(4))) float floatx4;

__device__ __forceinline__ float wave_max(float v){
  #pragma unroll
  for (int o = 32; o; o >>= 1) v = fmaxf(v, __shfl_xor(v, o));
  return v;
}
__device__ __forceinline__ float wave_sum(float v){
  #pragma unroll
  for (int o = 32; o; o >>= 1) v += __shfl_xor(v, o);
  return v;
}
__device__ __forceinline__ unsigned short f2bf(float f){
  union { float f; unsigned int u; } v; v.f = f;
  unsigned int r = v.u + 0x7FFFu + ((v.u >> 16) & 1u);
  return (unsigned short)(r >> 16);
}
__device__ __forceinline__ float bf2f(unsigned short h){
  union { unsigned int u; float f; } v; v.u = ((unsigned int)h) << 16; return v.f;
}

// ---------------- CSR build (dst-major, includes self loops) ----------------
__global__ void k_count(const int* __restrict__ ei, int* __restrict__ deg){
  int e = blockIdx.x * blockDim.x + threadIdx.x;
  if (e >= M_EDGES) return;
  int dst = (e < N_EDGES) ? ei[N_EDGES + e] : (e - N_EDGES);
  atomicAdd(&deg[dst], 1);
}
__global__ void k_alloc(const int* __restrict__ deg, int* __restrict__ row_start,
                        int* __restrict__ cursor){
  int n = blockIdx.x * blockDim.x + threadIdx.x;
  if (n >= N_NODES) return;
  row_start[n] = atomicAdd(cursor, deg[n]);
}
__global__ void k_fill(const int* __restrict__ ei, const int* __restrict__ row_start,
                       int* __restrict__ fill, int* __restrict__ col){
  int e = blockIdx.x * blockDim.x + threadIdx.x;
  if (e >= M_EDGES) return;
  int src, dst;
  if (e < N_EDGES){ src = ei[e]; dst = ei[N_EDGES + e]; }
  else { src = dst = e - N_EDGES; }
  int slot = row_start[dst] + atomicAdd(&fill[dst], 1);
  col[slot] = src;
}

// -------- fused prep: W1/W2 split-bf16 B^T panels + P projection ------------
__global__ __launch_bounds__(768) void k_prep(const float* __restrict__ W1,
                                              const float* __restrict__ W2,
                                              const float* __restrict__ as1,
                                              const float* __restrict__ ad1,
                                              unsigned short* __restrict__ W1B3t,
                                              unsigned short* __restrict__ W2B3t,
                                              float* __restrict__ P){
  const int b = blockIdx.x, k = threadIdx.x;
  if (b < 256){
    float w = W1[(size_t)(k & 255) * 256 + b];
    unsigned short hi = f2bf(w);
    W1B3t[(size_t)b * 768 + k] = (k < 512) ? hi : f2bf(w - bf2f(hi));
  } else if (b < 320){
    int n = b - 256;
    float w = W2[(size_t)(k & 255) * 64 + n];
    unsigned short hi = f2bf(w);
    W2B3t[(size_t)n * 768 + k] = (k < 512) ? hi : f2bf(w - bf2f(hi));
  } else if (k < 256){
    float acc[8] = {0.f,0.f,0.f,0.f,0.f,0.f,0.f,0.f};
    for (int c = 0; c < 64; ++c){
      #pragma unroll
      for (int h = 0; h < 4; ++h){
        float w = W1[k * 256 + h * 64 + c];
        acc[h]     += w * as1[h * 64 + c];
        acc[4 + h] += w * ad1[h * 64 + c];
      }
    }
    #pragma unroll
    for (int j = 0; j < 8; ++j) P[k * 8 + j] = acc[j];
  }
}

// --- attention scalars asrc/adst = x @ P, fused with x -> split-bf16 x2 -----
__global__ __launch_bounds__(256) void k_att1p(const float* __restrict__ x,
                                               const float* __restrict__ P,
                                               float* __restrict__ asrc,
                                               float* __restrict__ adst,
                                               unsigned short* __restrict__ x2){
  __shared__ float Ps[256][9];
  const int tid = threadIdx.x;
  #pragma unroll
  for (int j = 0; j < 8; ++j) Ps[tid][j] = P[tid * 8 + j];
  __syncthreads();
  const int n = blockIdx.x * 4 + (tid >> 6);
  const int lane = tid & 63;
  float4 xv = *(const float4*)&x[(size_t)n * 256 + lane * 4];
  ushort4 hi4, lo4;
  hi4.x = f2bf(xv.x); lo4.x = f2bf(xv.x - bf2f(hi4.x));
  hi4.y = f2bf(xv.y); lo4.y = f2bf(xv.y - bf2f(hi4.y));
  hi4.z = f2bf(xv.z); lo4.z = f2bf(xv.z - bf2f(hi4.z));
  hi4.w = f2bf(xv.w); lo4.w = f2bf(xv.w - bf2f(hi4.w));
  *(ushort4*)&x2[(size_t)n * 512 + lane * 4] = hi4;
  *(ushort4*)&x2[(size_t)n * 512 + 256 + lane * 4] = lo4;
  float p[8];
  #pragma unroll
  for (int j = 0; j < 8; ++j){
    p[j] = xv.x * Ps[lane * 4 + 0][j] + xv.y * Ps[lane * 4 + 1][j]
         + xv.z * Ps[lane * 4 + 2][j] + xv.w * Ps[lane * 4 + 3][j];
    p[j] = wave_sum(p[j]);
  }
  if (lane == 0){
    *(float4*)&asrc[n * 4] = make_float4(p[0], p[1], p[2], p[3]);
    *(float4*)&adst[n * 4] = make_float4(p[4], p[5], p[6], p[7]);
  }
}

// ------------- split-bf16 MFMA GEMM: C = A2(panels) @ Bt^T ------------------
template<int OUT_HALF>
__global__ __launch_bounds__(256) void mfma_gemm(const unsigned short* __restrict__ A,
                                                 const unsigned short* __restrict__ Bt,
                                                 void* __restrict__ Cout,
                                                 int M, int ldc){
  __shared__ unsigned short As[128 * 64];
  __shared__ unsigned short Bs[64 * 64];
  const int tid = threadIdx.x;
  const int m0 = blockIdx.y * 128, n0 = blockIdx.x * 64;
  floatx4 acc[4][2];
  #pragma unroll
  for (int mr = 0; mr < 4; ++mr)
    #pragma unroll
    for (int nr = 0; nr < 2; ++nr) acc[mr][nr] = (floatx4){0.f, 0.f, 0.f, 0.f};
  const int l = tid & 63, w = tid >> 6;
  const int wm = (w >> 1) * 64, wn = (w & 1) * 32;
  const int lr = l & 15;

  for (int kc = 0; kc < 768; kc += 64){
    #pragma unroll
    for (int i = 0; i < 4; ++i){
      int f = tid + i * 256, row = f >> 3, seg = f & 7;
      int sseg = seg ^ (row & 7);
      float4 v = make_float4(0.f, 0.f, 0.f, 0.f);
      if (m0 + row < M)
        v = *(const float4*)&A[(size_t)(m0 + row) * 512 + (kc & 511) + seg * 8];
      *(float4*)&As[row * 64 + sseg * 8] = v;
    }
    #pragma unroll
    for (int i = 0; i < 2; ++i){
      int f = tid + i * 256, row = f >> 3, seg = f & 7;
      int sseg = seg ^ (row & 7);
      *(float4*)&Bs[row * 64 + sseg * 8] =
        *(const float4*)&Bt[(size_t)(n0 + row) * 768 + kc + seg * 8];
    }
    __syncthreads();
    #pragma unroll
    for (int kk = 0; kk < 2; ++kk){
      const int seg = kk * 4 + (l >> 4);
      const int br0 = wn + lr, br1 = wn + 16 + lr;
      bfrag8 b0  = *(const bfrag8*)&Bs[br0 * 64 + (seg ^ (br0 & 7)) * 8];
      bfrag8 b1v = *(const bfrag8*)&Bs[br1 * 64 + (seg ^ (br1 & 7)) * 8];
      #pragma unroll
      for (int mr = 0; mr < 4; ++mr){
        const int ar = wm + mr * 16 + lr;
        bfrag8 a = *(const bfrag8*)&As[ar * 64 + (seg ^ (ar & 7)) * 8];
        acc[mr][0] = __builtin_amdgcn_mfma_f32_16x16x32_bf16(a, b0, acc[mr][0], 0, 0, 0);
        acc[mr][1] = __builtin_amdgcn_mfma_f32_16x16x32_bf16(a, b1v, acc[mr][1], 0, 0, 0);
      }
    }
    __syncthreads();
  }
  #pragma unroll
  for (int mr = 0; mr < 4; ++mr)
    #pragma unroll
    for (int nr = 0; nr < 2; ++nr){
      const int colg = n0 + wn + nr * 16 + lr;
      #pragma unroll
      for (int r = 0; r < 4; ++r){
        const int row = m0 + wm + mr * 16 + (l >> 4) * 4 + r;
        if (row < M){
          if (OUT_HALF)
            ((__half*)Cout)[(size_t)row * ldc + colg] = __float2half(acc[mr][nr][r]);
          else
            ((float*)Cout)[(size_t)row * ldc + colg] = acc[mr][nr][r];
        }
      }
    }
}

// ---- conv1 aggregate, WAVE-PER-NODE, online softmax, LDS-FREE --------------
// lane e owns edge e of the chunk; (src, weights) broadcast via __shfl only.
__global__ __launch_bounds__(256) void k_agg1w(const __half* __restrict__ h1,
                                               const int* __restrict__ col,
                                               const int* __restrict__ row_start,
                                               const int* __restrict__ degv,
                                               const float* __restrict__ asrc,
                                               const float* __restrict__ adst,
                                               const float* __restrict__ b1,
                                               unsigned short* __restrict__ out1s){
  const int tid = threadIdx.x, wv = tid >> 6, lane = tid & 63;
  const int n = blockIdx.x * 4 + wv;
  const int base = row_start[n], dg = degv[n];
  const float4 ad4 = *(const float4*)&adst[(size_t)n * 4];
  const int hsel = lane >> 4;
  float m0 = -3e38f, m1 = -3e38f, m2 = -3e38f, m3 = -3e38f;
  float s = 0.f;
  float4 acc = make_float4(0.f, 0.f, 0.f, 0.f);

  for (int c0 = 0; c0 < dg; c0 += 64){
    const int cnt = min(64, dg - c0);
    float e0 = -3e38f, e1 = -3e38f, e2 = -3e38f, e3 = -3e38f;
    int src = 0;
    if (lane < cnt){
      src = col[base + c0 + lane];
      const float4 s4 = *(const float4*)&asrc[(size_t)src * 4];
      e0 = s4.x + ad4.x; e0 = e0 > 0.f ? e0 : 0.2f * e0;
      e1 = s4.y + ad4.y; e1 = e1 > 0.f ? e1 : 0.2f * e1;
      e2 = s4.z + ad4.z; e2 = e2 > 0.f ? e2 : 0.2f * e2;
      e3 = s4.w + ad4.w; e3 = e3 > 0.f ? e3 : 0.2f * e3;
    }
    const float M0 = wave_max(e0), M1 = wave_max(e1), M2 = wave_max(e2), M3 = wave_max(e3);
    const float nm0 = fmaxf(m0, M0), nm1 = fmaxf(m1, M1);
    const float nm2 = fmaxf(m2, M2), nm3 = fmaxf(m3, M3);
    const float mo = hsel == 0 ? m0 : hsel == 1 ? m1 : hsel == 2 ? m2 : m3;
    const float mn = hsel == 0 ? nm0 : hsel == 1 ? nm1 : hsel == 2 ? nm2 : nm3;
    const float r = __expf(mo - mn);   // 0 on first chunk
    s *= r; acc.x *= r; acc.y *= r; acc.z *= r; acc.w *= r;
    m0 = nm0; m1 = nm1; m2 = nm2; m3 = nm3;
    // per-lane edge weights for all 4 heads (inactive lanes -> 0)
    const float w0 = __expf(e0 - nm0), w1 = __expf(e1 - nm1);
    const float w2 = __expf(e2 - nm2), w3 = __expf(e3 - nm3);
    const float S0 = wave_sum(w0), S1 = wave_sum(w1);
    const float S2 = wave_sum(w2), S3 = wave_sum(w3);
    s += hsel == 0 ? S0 : hsel == 1 ? S1 : hsel == 2 ? S2 : S3;
    // gather: broadcast edge j's (src, head-weight) via shuffles
    int j = 0;
    for (; j + 4 <= cnt; j += 4){
      float wt[4]; int sj[4];
      #pragma unroll
      for (int u = 0; u < 4; ++u){
        const float t0 = __shfl(w0, j + u), t1 = __shfl(w1, j + u);
        const float t2 = __shfl(w2, j + u), t3 = __shfl(w3, j + u);
        wt[u] = hsel == 0 ? t0 : hsel == 1 ? t1 : hsel == 2 ? t2 : t3;
        sj[u] = __shfl(src, j + u);
      }
      uint2 rw[4];
      #pragma unroll
      for (int u = 0; u < 4; ++u)
        rw[u] = *(const uint2*)&h1[(size_t)sj[u] * 256 + lane * 4];
      #pragma unroll
      for (int u = 0; u < 4; ++u){
        float2 f01 = __half22float2(*reinterpret_cast<const __half2*>(&rw[u].x));
        float2 f23 = __half22float2(*reinterpret_cast<const __half2*>(&rw[u].y));
        acc.x += wt[u] * f01.x; acc.y += wt[u] * f01.y;
        acc.z += wt[u] * f23.x; acc.w += wt[u] * f23.y;
      }
    }
    for (; j < cnt; ++j){
      const float t0 = __shfl(w0, j), t1 = __shfl(w1, j);
      const float t2 = __shfl(w2, j), t3 = __shfl(w3, j);
      const float wt = hsel == 0 ? t0 : hsel == 1 ? t1 : hsel == 2 ? t2 : t3;
      const int sj = __shfl(src, j);
      const uint2 rw = *(const uint2*)&h1[(size_t)sj * 256 + lane * 4];
      float2 f01 = __half22float2(*reinterpret_cast<const __half2*>(&rw.x));
      float2 f23 = __half22float2(*reinterpret_cast<const __half2*>(&rw.y));
      acc.x += wt * f01.x; acc.y += wt * f01.y;
      acc.z += wt * f23.x; acc.w += wt * f23.y;
    }
  }
  const float inv = 1.f / (s + 1e-16f);
  const float4 bb = *(const float4*)&b1[lane * 4];
  float o0 = acc.x * inv + bb.x; o0 = o0 > 0.f ? o0 : __expf(o0) - 1.f;
  float o1 = acc.y * inv + bb.y; o1 = o1 > 0.f ? o1 : __expf(o1) - 1.f;
  float o2 = acc.z * inv + bb.z; o2 = o2 > 0.f ? o2 : __expf(o2) - 1.f;
  float o3 = acc.w * inv + bb.w; o3 = o3 > 0.f ? o3 : __expf(o3) - 1.f;
  ushort4 hi4, lo4;
  hi4.x = f2bf(o0); lo4.x = f2bf(o0 - bf2f(hi4.x));
  hi4.y = f2bf(o1); lo4.y = f2bf(o1 - bf2f(hi4.y));
  hi4.z = f2bf(o2); lo4.z = f2bf(o2 - bf2f(hi4.z));
  hi4.w = f2bf(o3); lo4.w = f2bf(o3 - bf2f(hi4.w));
  *(ushort4*)&out1s[(size_t)n * 512 + lane * 4] = hi4;
  *(ushort4*)&out1s[(size_t)n * 512 + 256 + lane * 4] = lo4;
}

// ------------- conv2 attention scalars (4 nodes/block, fp16 t2) -------------
__global__ __launch_bounds__(256) void k_att2(const __half* __restrict__ t2,
                                              const float* __restrict__ a_src,
                                              const float* __restrict__ a_dst,
                                              float* __restrict__ asrc,
                                              float* __restrict__ adst){
  const int tid = threadIdx.x, wv = tid >> 6, lane = tid & 63;
  const int n = blockIdx.x * 4 + wv;
  float v = __half2float(t2[(size_t)n * 64 + lane]);
  float ps = wave_sum(v * a_src[lane]);
  float pd = wave_sum(v * a_dst[lane]);
  if (lane == 0){ asrc[n] = ps; adst[n] = pd; }
}

// ---- conv2 aggregate, WAVE-PER-NODE, LDS-FREE (2 edges/iter) ---------------
__global__ __launch_bounds__(256) void k_agg2w(const __half* __restrict__ t2,
                                               const int* __restrict__ col,
                                               const int* __restrict__ row_start,
                                               const int* __restrict__ degv,
                                               const float* __restrict__ asrc,
                                               const float* __restrict__ adst,
                                               const float* __restrict__ b2,
                                               const float* __restrict__ Wg,
                                               const float* __restrict__ bg,
                                               float* __restrict__ hf,
                                               float* __restrict__ attg){
  const int tid = threadIdx.x, wv = tid >> 6, lane = tid & 63;
  const int n = blockIdx.x * 4 + wv;
  const int base = row_start[n], dg = degv[n];
  const float ad = adst[n];
  const int half = lane >> 5, c2 = lane & 31;  // channel pair 2*c2, 2*c2+1
  float m = -3e38f, s = 0.f;
  float2 acc = make_float2(0.f, 0.f);

  for (int c0 = 0; c0 < dg; c0 += 64){
    const int cnt = min(64, dg - c0);
    float e = -3e38f; int src = 0;
    if (lane < cnt){
      src = col[base + c0 + lane];
      e = asrc[src] + ad;
      e = e > 0.f ? e : 0.2f * e;
    }
    const float M = wave_max(e);
    const float mn = fmaxf(m, M);
    const float r = __expf(m - mn);
    s *= r; acc.x *= r; acc.y *= r;
    m = mn;
    const float w = __expf(e - mn);   // inactive lanes -> 0
    s += wave_sum(w);
    for (int j = 0; j < cnt; j += 2){
      const int j0 = j + half;
      if (j0 < cnt){
        const float wt = __shfl(w, j0);
        const int sj = __shfl(src, j0);
        const unsigned int rw = *(const unsigned int*)&t2[(size_t)sj * 64 + c2 * 2];
        float2 f = __half22float2(*reinterpret_cast<const __half2*>(&rw));
        acc.x += wt * f.x; acc.y += wt * f.y;
      }
    }
  }
  acc.x += __shfl_xor(acc.x, 32);
  acc.y += __shfl_xor(acc.y, 32);
  const float inv = 1.f / (s + 1e-16f);
  float p = 0.f;
  if (half == 0){
    float o0 = acc.x * inv + b2[c2 * 2];     o0 = o0 > 0.f ? o0 : __expf(o0) - 1.f;
    float o1 = acc.y * inv + b2[c2 * 2 + 1]; o1 = o1 > 0.f ? o1 : __expf(o1) - 1.f;
    *(float2*)&hf[(size_t)n * 64 + c2 * 2] = make_float2(o0, o1);
    p = o0 * Wg[c2 * 2] + o1 * Wg[c2 * 2 + 1];
  }
  p = wave_sum(p);
  if (lane == 0) attg[n] = p + bg[0];
}

// --------- per-graph softmax pooling + 2-layer classifier -------------------
__global__ __launch_bounds__(64) void k_pool(const float* __restrict__ hf,
                                             const float* __restrict__ attg,
                                             const int* __restrict__ batch,
                                             const float* __restrict__ Wc1,
                                             const float* __restrict__ bc1,
                                             const float* __restrict__ Wc2,
                                             const float* __restrict__ bc2,
                                             float* __restrict__ out){
  __shared__ float pooled[64];
  __shared__ float hid[32];
  const int g = blockIdx.x, lane = threadIdx.x;
  int lo = 0, hi = N_NODES;
  while (lo < hi){ int mid = (lo + hi) >> 1; if (batch[mid] < g) lo = mid + 1; else hi = mid; }
  const int s0 = lo;
  hi = N_NODES;
  while (lo < hi){ int mid = (lo + hi) >> 1; if (batch[mid] < g + 1) lo = mid + 1; else hi = mid; }
  const int s1 = lo;
  float lm = -3e38f;
  for (int j = s0 + lane; j < s1; j += 64) lm = fmaxf(lm, attg[j]);
  lm = wave_max(lm);
  float ls = 0.f;
  for (int j = s0 + lane; j < s1; j += 64) ls += __expf(attg[j] - lm);
  ls = wave_sum(ls);
  const float inv = 1.f / (ls + 1e-16f);
  float acc = 0.f;
  for (int j = s0; j < s1; ++j)
    acc += __expf(attg[j] - lm) * hf[(size_t)j * 64 + lane];
  pooled[lane] = acc * inv;
  __syncthreads();
  if (lane < 32){
    float t = bc1[lane];
    #pragma unroll
    for (int c = 0; c < 64; ++c) t += pooled[c] * Wc1[c * 32 + lane];
    hid[lane] = t > 0.f ? t : 0.f;
  }
  __syncthreads();
  if (lane < 2){
    float t = bc2[lane];
    #pragma unroll
    for (int c = 0; c < 32; ++c) t += hid[c] * Wc2[c * 2 + lane];
    out[g * 2 + lane] = t;
  }
}

extern "C" void kernel_launch(void* const* d_in, const int* in_sizes, int n_in,
                              void* d_out, int out_size, void* d_ws, size_t ws_size,
                              hipStream_t stream){
  const float* x    = (const float*)d_in[0];
  const int*   ei   = (const int*)d_in[1];
  const int*   batch= (const int*)d_in[2];
  const float* W1   = (const float*)d_in[3];
  const float* as1  = (const float*)d_in[4];
  const float* ad1  = (const float*)d_in[5];
  const float* b1   = (const float*)d_in[6];
  const float* W2   = (const float*)d_in[7];
  const float* as2  = (const float*)d_in[8];
  const float* ad2  = (const float*)d_in[9];
  const float* b2   = (const float*)d_in[10];
  const float* Wg   = (const float*)d_in[11];
  const float* bg   = (const float*)d_in[12];
  const float* Wc1  = (const float*)d_in[13];
  const float* bc1  = (const float*)d_in[14];
  const float* Wc2  = (const float*)d_in[15];
  const float* bc2  = (const float*)d_in[16];

  char* ws = (char*)d_ws;
  unsigned short* x2s   = (unsigned short*)(ws + 0LL);         // [N][512] bf16 split
  unsigned short* out1s = (unsigned short*)(ws + 0LL);         // same region (x2 dead after gemm1)
  __half* h1h   = (__half*)(ws + 51200000LL);   // [N][256] fp16 = 25.6MB
  __half* t2h   = (__half*)(ws + 102400000LL);  // [N][64] fp16 = 6.4MB
  float* hf     = (float*)(ws + 115200000LL);   // 12.8MB (written late by k_agg2w)
  float* P      = (float*)(ws + 115200000LL);   // 8KB (dead before hf written)
  unsigned short* W1B3t = (unsigned short*)(ws + 115208192LL); // 393216B
  unsigned short* W2B3t = (unsigned short*)(ws + 115601408LL); // 98304B
  float* asrc1  = (float*)(ws + 128000000LL);   // 800KB
  float* adst1  = (float*)(ws + 128800000LL);   // 800KB
  float* asrc2  = (float*)(ws + 129600000LL);   // 200KB
  float* adst2  = (float*)(ws + 129800000LL);   // 200KB
  float* attg   = (float*)(ws + 130000000LL);   // 200KB
  int*   deg    = (int*)  (ws + 130200000LL);   // 200KB
  int*   fill   = (int*)  (ws + 130400000LL);   // 200KB
  int*   cursor = (int*)  (ws + 130600000LL);   // 256B
  int*   row_st = (int*)  (ws + 130600256LL);   // 200KB
  int*   col    = (int*)  (ws + 130800256LL);   // 3.4MB
  float* outf   = (float*)d_out;

  hipMemsetAsync(ws + 130200000LL, 0, 400256, stream);

  k_count<<<(M_EDGES + 255) / 256, 256, 0, stream>>>(ei, deg);
  k_alloc<<<(N_NODES + 255) / 256, 256, 0, stream>>>(deg, row_st, cursor);
  k_fill<<<(M_EDGES + 255) / 256, 256, 0, stream>>>(ei, row_st, fill, col);

  k_prep<<<321, 768, 0, stream>>>(W1, W2, as1, ad1, W1B3t, W2B3t, P);
  k_att1p<<<N_NODES / 4, 256, 0, stream>>>(x, P, asrc1, adst1, x2s);

  mfma_gemm<1><<<dim3(4, 391), 256, 0, stream>>>(x2s, W1B3t, (void*)h1h, N_NODES, 256);
  k_agg1w<<<N_NODES / 4, 256, 0, stream>>>(h1h, col, row_st, deg, asrc1, adst1, b1, out1s);

  mfma_gemm<1><<<dim3(1, 391), 256, 0, stream>>>(out1s, W2B3t, (void*)t2h, N_NODES, 64);
  k_att2<<<N_NODES / 4, 256, 0, stream>>>(t2h, as2, ad2, asrc2, adst2);
  k_agg2w<<<N_NODES / 4, 256, 0, stream>>>(t2h, col, row_st, deg, asrc2, adst2, b2, Wg, bg, hf, attg);

  k_pool<<<NGRAPH, 64, 0, stream>>>(hf, attg, batch, Wc1, bc1, Wc2, bc2, outf);
}

// Round 10
// 504.252 us; speedup vs baseline: 1.2510x; 1.0093x over previous
//
#include <hip/hip_runtime.h>
#include <hip/hip_bf16.h>
#include <hip/hip_fp16.h>
#include <math.h>

#define N_NODES 50000
#define N_EDGES 800000
#define M_EDGES (N_EDGES + N_NODES)
#define NGRAPH 512

typedef __attribute__((ext_vector_type(8))) short bfrag8;
typedef __attribute__((ext_vector_type(4))) float floatx4;

__device__ __forceinline__ float wave_max(float v){
  #pragma unroll
  for (int o = 32; o; o >>= 1) v = fmaxf(v, __shfl_xor(v, o));
  return v;
}
__device__ __forceinline__ float wave_sum(float v){
  #pragma unroll
  for (int o = 32; o; o >>= 1) v += __shfl_xor(v, o);
  return v;
}
__device__ __forceinline__ unsigned short f2bf(float f){
  union { float f; unsigned int u; } v; v.f = f;
  unsigned int r = v.u + 0x7FFFu + ((v.u >> 16) & 1u);
  return (unsigned short)(r >> 16);
}
__device__ __forceinline__ float bf2f(unsigned short h){
  union { unsigned int u; float f; } v; v.u = ((unsigned int)h) << 16; return v.f;
}

// ---------------- CSR build (dst-major, includes self loops) ----------------
__global__ void k_count(const int* __restrict__ ei, int* __restrict__ deg){
  int e = blockIdx.x * blockDim.x + threadIdx.x;
  if (e >= M_EDGES) return;
  int dst = (e < N_EDGES) ? ei[N_EDGES + e] : (e - N_EDGES);
  atomicAdd(&deg[dst], 1);
}

// exclusive prefix scan of deg -> row_start, single block, 1024 threads
__global__ __launch_bounds__(1024) void k_scan(const int* __restrict__ deg,
                                               int* __restrict__ row_start){
  __shared__ int wsum[16];
  __shared__ int carry;
  const int tid = threadIdx.x, lane = tid & 63, wv = tid >> 6;
  if (tid == 0) carry = 0;
  __syncthreads();
  for (int b = 0; b < N_NODES; b += 1024){
    const int i = b + tid;
    const int v = (i < N_NODES) ? deg[i] : 0;
    int x = v;
    #pragma unroll
    for (int o = 1; o < 64; o <<= 1){
      int t = __shfl_up(x, o);
      if (lane >= o) x += t;
    }
    if (lane == 63) wsum[wv] = x;
    __syncthreads();
    if (tid == 0){
      int run = carry;
      #pragma unroll
      for (int k = 0; k < 16; ++k){ int t = wsum[k]; wsum[k] = run; run += t; }
      carry = run;
    }
    __syncthreads();
    if (i < N_NODES) row_start[i] = wsum[wv] + x - v;
    __syncthreads();
  }
}

__global__ void k_fill(const int* __restrict__ ei, const int* __restrict__ row_start,
                       int* __restrict__ fill, int* __restrict__ col){
  int e = blockIdx.x * blockDim.x + threadIdx.x;
  if (e >= M_EDGES) return;
  int src, dst;
  if (e < N_EDGES){ src = ei[e]; dst = ei[N_EDGES + e]; }
  else { src = dst = e - N_EDGES; }
  int slot = row_start[dst] + atomicAdd(&fill[dst], 1);
  col[slot] = src;
}

// -------- fused prep: W1/W2 split-bf16 B^T panels + P projection ------------
__global__ __launch_bounds__(768) void k_prep(const float* __restrict__ W1,
                                              const float* __restrict__ W2,
                                              const float* __restrict__ as1,
                                              const float* __restrict__ ad1,
                                              unsigned short* __restrict__ W1B3t,
                                              unsigned short* __restrict__ W2B3t,
                                              float* __restrict__ P){
  const int b = blockIdx.x, k = threadIdx.x;
  if (b < 256){
    float w = W1[(size_t)(k & 255) * 256 + b];
    unsigned short hi = f2bf(w);
    W1B3t[(size_t)b * 768 + k] = (k < 512) ? hi : f2bf(w - bf2f(hi));
  } else if (b < 320){
    int n = b - 256;
    float w = W2[(size_t)(k & 255) * 64 + n];
    unsigned short hi = f2bf(w);
    W2B3t[(size_t)n * 768 + k] = (k < 512) ? hi : f2bf(w - bf2f(hi));
  } else if (k < 256){
    float acc[8] = {0.f,0.f,0.f,0.f,0.f,0.f,0.f,0.f};
    for (int c = 0; c < 64; ++c){
      #pragma unroll
      for (int h = 0; h < 4; ++h){
        float w = W1[k * 256 + h * 64 + c];
        acc[h]     += w * as1[h * 64 + c];
        acc[4 + h] += w * ad1[h * 64 + c];
      }
    }
    #pragma unroll
    for (int j = 0; j < 8; ++j) P[k * 8 + j] = acc[j];
  }
}

// --- attention scalars asrc/adst = x @ P, fused with x -> split-bf16 x2 -----
__global__ __launch_bounds__(256) void k_att1p(const float* __restrict__ x,
                                               const float* __restrict__ P,
                                               float* __restrict__ asrc,
                                               float* __restrict__ adst,
                                               unsigned short* __restrict__ x2){
  __shared__ float Ps[256][9];
  const int tid = threadIdx.x;
  #pragma unroll
  for (int j = 0; j < 8; ++j) Ps[tid][j] = P[tid * 8 + j];
  __syncthreads();
  const int n = blockIdx.x * 4 + (tid >> 6);
  const int lane = tid & 63;
  float4 xv = *(const float4*)&x[(size_t)n * 256 + lane * 4];
  ushort4 hi4, lo4;
  hi4.x = f2bf(xv.x); lo4.x = f2bf(xv.x - bf2f(hi4.x));
  hi4.y = f2bf(xv.y); lo4.y = f2bf(xv.y - bf2f(hi4.y));
  hi4.z = f2bf(xv.z); lo4.z = f2bf(xv.z - bf2f(hi4.z));
  hi4.w = f2bf(xv.w); lo4.w = f2bf(xv.w - bf2f(hi4.w));
  *(ushort4*)&x2[(size_t)n * 512 + lane * 4] = hi4;
  *(ushort4*)&x2[(size_t)n * 512 + 256 + lane * 4] = lo4;
  float p[8];
  #pragma unroll
  for (int j = 0; j < 8; ++j){
    p[j] = xv.x * Ps[lane * 4 + 0][j] + xv.y * Ps[lane * 4 + 1][j]
         + xv.z * Ps[lane * 4 + 2][j] + xv.w * Ps[lane * 4 + 3][j];
    p[j] = wave_sum(p[j]);
  }
  if (lane == 0){
    *(float4*)&asrc[n * 4] = make_float4(p[0], p[1], p[2], p[3]);
    *(float4*)&adst[n * 4] = make_float4(p[4], p[5], p[6], p[7]);
  }
}

// ------------- split-bf16 MFMA GEMM: C = A2(panels) @ Bt^T ------------------
// BM=128, BN template (64 or 128), BK=64, 256 threads (2x2 waves).
// LDS XOR-swizzled in 16B segments (seg ^= row&7) on write and read sides.
template<int BN, int OUT_HALF>
__global__ __launch_bounds__(256) void mfma_gemm(const unsigned short* __restrict__ A,
                                                 const unsigned short* __restrict__ Bt,
                                                 void* __restrict__ Cout,
                                                 int M, int ldc){
  __shared__ unsigned short As[128 * 64];
  __shared__ unsigned short Bs[BN * 64];
  const int tid = threadIdx.x;
  const int m0 = blockIdx.y * 128, n0 = blockIdx.x * BN;
  constexpr int NR = BN / 32;      // n-frags per wave
  floatx4 acc[4][NR];
  #pragma unroll
  for (int mr = 0; mr < 4; ++mr)
    #pragma unroll
    for (int nr = 0; nr < NR; ++nr) acc[mr][nr] = (floatx4){0.f, 0.f, 0.f, 0.f};
  const int l = tid & 63, w = tid >> 6;
  const int wm = (w >> 1) * 64, wn = (w & 1) * (BN / 2);
  const int lr = l & 15;

  for (int kc = 0; kc < 768; kc += 64){
    #pragma unroll
    for (int i = 0; i < 4; ++i){
      int f = tid + i * 256, row = f >> 3, seg = f & 7;
      int sseg = seg ^ (row & 7);
      float4 v = make_float4(0.f, 0.f, 0.f, 0.f);
      if (m0 + row < M)
        v = *(const float4*)&A[(size_t)(m0 + row) * 512 + (kc & 511) + seg * 8];
      *(float4*)&As[row * 64 + sseg * 8] = v;
    }
    #pragma unroll
    for (int i = 0; i < BN / 32; ++i){
      int f = tid + i * 256, row = f >> 3, seg = f & 7;
      int sseg = seg ^ (row & 7);
      *(float4*)&Bs[row * 64 + sseg * 8] =
        *(const float4*)&Bt[(size_t)(n0 + row) * 768 + kc + seg * 8];
    }
    __syncthreads();
    #pragma unroll
    for (int kk = 0; kk < 2; ++kk){
      const int seg = kk * 4 + (l >> 4);
      bfrag8 bfr[NR];
      #pragma unroll
      for (int nr = 0; nr < NR; ++nr){
        const int br = wn + nr * 16 + lr;
        bfr[nr] = *(const bfrag8*)&Bs[br * 64 + (seg ^ (br & 7)) * 8];
      }
      #pragma unroll
      for (int mr = 0; mr < 4; ++mr){
        const int ar = wm + mr * 16 + lr;
        bfrag8 a = *(const bfrag8*)&As[ar * 64 + (seg ^ (ar & 7)) * 8];
        #pragma unroll
        for (int nr = 0; nr < NR; ++nr)
          acc[mr][nr] = __builtin_amdgcn_mfma_f32_16x16x32_bf16(a, bfr[nr], acc[mr][nr], 0, 0, 0);
      }
    }
    __syncthreads();
  }
  #pragma unroll
  for (int mr = 0; mr < 4; ++mr)
    #pragma unroll
    for (int nr = 0; nr < NR; ++nr){
      const int colg = n0 + wn + nr * 16 + lr;
      #pragma unroll
      for (int r = 0; r < 4; ++r){
        const int row = m0 + wm + mr * 16 + (l >> 4) * 4 + r;
        if (row < M){
          if (OUT_HALF)
            ((__half*)Cout)[(size_t)row * ldc + colg] = __float2half(acc[mr][nr][r]);
          else
            ((float*)Cout)[(size_t)row * ldc + colg] = acc[mr][nr][r];
        }
      }
    }
}

// ---- conv1 aggregate, WAVE-PER-NODE, online softmax, LDS-FREE --------------
__global__ __launch_bounds__(256) void k_agg1w(const __half* __restrict__ h1,
                                               const int* __restrict__ col,
                                               const int* __restrict__ row_start,
                                               const int* __restrict__ degv,
                                               const float* __restrict__ asrc,
                                               const float* __restrict__ adst,
                                               const float* __restrict__ b1,
                                               unsigned short* __restrict__ out1s){
  const int tid = threadIdx.x, wv = tid >> 6, lane = tid & 63;
  const int n = blockIdx.x * 4 + wv;
  const int base = row_start[n], dg = degv[n];
  const float4 ad4 = *(const float4*)&adst[(size_t)n * 4];
  const int hsel = lane >> 4;
  float m0 = -3e38f, m1 = -3e38f, m2 = -3e38f, m3 = -3e38f;
  float s = 0.f;
  float4 acc = make_float4(0.f, 0.f, 0.f, 0.f);

  for (int c0 = 0; c0 < dg; c0 += 64){
    const int cnt = min(64, dg - c0);
    float e0 = -3e38f, e1 = -3e38f, e2 = -3e38f, e3 = -3e38f;
    int src = 0;
    if (lane < cnt){
      src = col[base + c0 + lane];
      const float4 s4 = *(const float4*)&asrc[(size_t)src * 4];
      e0 = s4.x + ad4.x; e0 = e0 > 0.f ? e0 : 0.2f * e0;
      e1 = s4.y + ad4.y; e1 = e1 > 0.f ? e1 : 0.2f * e1;
      e2 = s4.z + ad4.z; e2 = e2 > 0.f ? e2 : 0.2f * e2;
      e3 = s4.w + ad4.w; e3 = e3 > 0.f ? e3 : 0.2f * e3;
    }
    const float M0 = wave_max(e0), M1 = wave_max(e1), M2 = wave_max(e2), M3 = wave_max(e3);
    const float nm0 = fmaxf(m0, M0), nm1 = fmaxf(m1, M1);
    const float nm2 = fmaxf(m2, M2), nm3 = fmaxf(m3, M3);
    const float mo = hsel == 0 ? m0 : hsel == 1 ? m1 : hsel == 2 ? m2 : m3;
    const float mn = hsel == 0 ? nm0 : hsel == 1 ? nm1 : hsel == 2 ? nm2 : nm3;
    const float r = __expf(mo - mn);   // 0 on first chunk
    s *= r; acc.x *= r; acc.y *= r; acc.z *= r; acc.w *= r;
    m0 = nm0; m1 = nm1; m2 = nm2; m3 = nm3;
    const float w0 = __expf(e0 - nm0), w1 = __expf(e1 - nm1);
    const float w2 = __expf(e2 - nm2), w3 = __expf(e3 - nm3);
    const float S0 = wave_sum(w0), S1 = wave_sum(w1);
    const float S2 = wave_sum(w2), S3 = wave_sum(w3);
    s += hsel == 0 ? S0 : hsel == 1 ? S1 : hsel == 2 ? S2 : S3;
    int j = 0;
    for (; j + 4 <= cnt; j += 4){
      float wt[4]; int sj[4];
      #pragma unroll
      for (int u = 0; u < 4; ++u){
        const float t0 = __shfl(w0, j + u), t1 = __shfl(w1, j + u);
        const float t2 = __shfl(w2, j + u), t3 = __shfl(w3, j + u);
        wt[u] = hsel == 0 ? t0 : hsel == 1 ? t1 : hsel == 2 ? t2 : t3;
        sj[u] = __shfl(src, j + u);
      }
      uint2 rw[4];
      #pragma unroll
      for (int u = 0; u < 4; ++u)
        rw[u] = *(const uint2*)&h1[(size_t)sj[u] * 256 + lane * 4];
      #pragma unroll
      for (int u = 0; u < 4; ++u){
        float2 f01 = __half22float2(*reinterpret_cast<const __half2*>(&rw[u].x));
        float2 f23 = __half22float2(*reinterpret_cast<const __half2*>(&rw[u].y));
        acc.x += wt[u] * f01.x; acc.y += wt[u] * f01.y;
        acc.z += wt[u] * f23.x; acc.w += wt[u] * f23.y;
      }
    }
    for (; j < cnt; ++j){
      const float t0 = __shfl(w0, j), t1 = __shfl(w1, j);
      const float t2 = __shfl(w2, j), t3 = __shfl(w3, j);
      const float wt = hsel == 0 ? t0 : hsel == 1 ? t1 : hsel == 2 ? t2 : t3;
      const int sj = __shfl(src, j);
      const uint2 rw = *(const uint2*)&h1[(size_t)sj * 256 + lane * 4];
      float2 f01 = __half22float2(*reinterpret_cast<const __half2*>(&rw.x));
      float2 f23 = __half22float2(*reinterpret_cast<const __half2*>(&rw.y));
      acc.x += wt * f01.x; acc.y += wt * f01.y;
      acc.z += wt * f23.x; acc.w += wt * f23.y;
    }
  }
  const float inv = 1.f / (s + 1e-16f);
  const float4 bb = *(const float4*)&b1[lane * 4];
  float o0 = acc.x * inv + bb.x; o0 = o0 > 0.f ? o0 : __expf(o0) - 1.f;
  float o1 = acc.y * inv + bb.y; o1 = o1 > 0.f ? o1 : __expf(o1) - 1.f;
  float o2 = acc.z * inv + bb.z; o2 = o2 > 0.f ? o2 : __expf(o2) - 1.f;
  float o3 = acc.w * inv + bb.w; o3 = o3 > 0.f ? o3 : __expf(o3) - 1.f;
  ushort4 hi4, lo4;
  hi4.x = f2bf(o0); lo4.x = f2bf(o0 - bf2f(hi4.x));
  hi4.y = f2bf(o1); lo4.y = f2bf(o1 - bf2f(hi4.y));
  hi4.z = f2bf(o2); lo4.z = f2bf(o2 - bf2f(hi4.z));
  hi4.w = f2bf(o3); lo4.w = f2bf(o3 - bf2f(hi4.w));
  *(ushort4*)&out1s[(size_t)n * 512 + lane * 4] = hi4;
  *(ushort4*)&out1s[(size_t)n * 512 + 256 + lane * 4] = lo4;
}

// ------------- conv2 attention scalars (4 nodes/block, fp16 t2) -------------
__global__ __launch_bounds__(256) void k_att2(const __half* __restrict__ t2,
                                              const float* __restrict__ a_src,
                                              const float* __restrict__ a_dst,
                                              float* __restrict__ asrc,
                                              float* __restrict__ adst){
  const int tid = threadIdx.x, wv = tid >> 6, lane = tid & 63;
  const int n = blockIdx.x * 4 + wv;
  float v = __half2float(t2[(size_t)n * 64 + lane]);
  float ps = wave_sum(v * a_src[lane]);
  float pd = wave_sum(v * a_dst[lane]);
  if (lane == 0){ asrc[n] = ps; adst[n] = pd; }
}

// ---- conv2 aggregate, WAVE-PER-NODE, LDS-FREE (2 edges/iter) ---------------
__global__ __launch_bounds__(256) void k_agg2w(const __half* __restrict__ t2,
                                               const int* __restrict__ col,
                                               const int* __restrict__ row_start,
                                               const int* __restrict__ degv,
                                               const float* __restrict__ asrc,
                                               const float* __restrict__ adst,
                                               const float* __restrict__ b2,
                                               const float* __restrict__ Wg,
                                               const float* __restrict__ bg,
                                               float* __restrict__ hf,
                                               float* __restrict__ attg){
  const int tid = threadIdx.x, wv = tid >> 6, lane = tid & 63;
  const int n = blockIdx.x * 4 + wv;
  const int base = row_start[n], dg = degv[n];
  const float ad = adst[n];
  const int half = lane >> 5, c2 = lane & 31;
  float m = -3e38f, s = 0.f;
  float2 acc = make_float2(0.f, 0.f);

  for (int c0 = 0; c0 < dg; c0 += 64){
    const int cnt = min(64, dg - c0);
    float e = -3e38f; int src = 0;
    if (lane < cnt){
      src = col[base + c0 + lane];
      e = asrc[src] + ad;
      e = e > 0.f ? e : 0.2f * e;
    }
    const float M = wave_max(e);
    const float mn = fmaxf(m, M);
    const float r = __expf(m - mn);
    s *= r; acc.x *= r; acc.y *= r;
    m = mn;
    const float w = __expf(e - mn);
    s += wave_sum(w);
    for (int j = 0; j < cnt; j += 2){
      const int j0 = j + half;
      if (j0 < cnt){
        const float wt = __shfl(w, j0);
        const int sj = __shfl(src, j0);
        const unsigned int rw = *(const unsigned int*)&t2[(size_t)sj * 64 + c2 * 2];
        float2 f = __half22float2(*reinterpret_cast<const __half2*>(&rw));
        acc.x += wt * f.x; acc.y += wt * f.y;
      }
    }
  }
  acc.x += __shfl_xor(acc.x, 32);
  acc.y += __shfl_xor(acc.y, 32);
  const float inv = 1.f / (s + 1e-16f);
  float p = 0.f;
  if (half == 0){
    float o0 = acc.x * inv + b2[c2 * 2];     o0 = o0 > 0.f ? o0 : __expf(o0) - 1.f;
    float o1 = acc.y * inv + b2[c2 * 2 + 1]; o1 = o1 > 0.f ? o1 : __expf(o1) - 1.f;
    *(float2*)&hf[(size_t)n * 64 + c2 * 2] = make_float2(o0, o1);
    p = o0 * Wg[c2 * 2] + o1 * Wg[c2 * 2 + 1];
  }
  p = wave_sum(p);
  if (lane == 0) attg[n] = p + bg[0];
}

// ----- per-graph softmax pooling + classifier, 4 waves per graph ------------
__global__ __launch_bounds__(256) void k_pool(const float* __restrict__ hf,
                                              const float* __restrict__ attg,
                                              const int* __restrict__ batch,
                                              const float* __restrict__ Wc1,
                                              const float* __restrict__ bc1,
                                              const float* __restrict__ Wc2,
                                              const float* __restrict__ bc2,
                                              float* __restrict__ out){
  __shared__ float redm[4], reds[4];
  __shared__ float pacc[4][64];
  __shared__ float pooled[64];
  __shared__ float hid[32];
  const int g = blockIdx.x, tid = threadIdx.x;
  const int wv = tid >> 6, lane = tid & 63;
  int lo = 0, hi = N_NODES;
  while (lo < hi){ int mid = (lo + hi) >> 1; if (batch[mid] < g) lo = mid + 1; else hi = mid; }
  const int s0 = lo;
  hi = N_NODES;
  while (lo < hi){ int mid = (lo + hi) >> 1; if (batch[mid] < g + 1) lo = mid + 1; else hi = mid; }
  const int s1 = lo;
  float lm = -3e38f;
  for (int j = s0 + tid; j < s1; j += 256) lm = fmaxf(lm, attg[j]);
  lm = wave_max(lm);
  if (lane == 0) redm[wv] = lm;
  __syncthreads();
  lm = fmaxf(fmaxf(redm[0], redm[1]), fmaxf(redm[2], redm[3]));
  float ls = 0.f;
  for (int j = s0 + tid; j < s1; j += 256) ls += __expf(attg[j] - lm);
  ls = wave_sum(ls);
  if (lane == 0) reds[wv] = ls;
  __syncthreads();
  ls = reds[0] + reds[1] + reds[2] + reds[3];
  const float inv = 1.f / (ls + 1e-16f);
  float acc = 0.f;
  for (int j = s0 + wv; j < s1; j += 4)
    acc += __expf(attg[j] - lm) * hf[(size_t)j * 64 + lane];
  pacc[wv][lane] = acc;
  __syncthreads();
  if (tid < 64)
    pooled[tid] = (pacc[0][tid] + pacc[1][tid] + pacc[2][tid] + pacc[3][tid]) * inv;
  __syncthreads();
  if (tid < 32){
    float t = bc1[tid];
    #pragma unroll
    for (int c = 0; c < 64; ++c) t += pooled[c] * Wc1[c * 32 + tid];
    hid[tid] = t > 0.f ? t : 0.f;
  }
  __syncthreads();
  if (tid < 2){
    float t = bc2[tid];
    #pragma unroll
    for (int c = 0; c < 32; ++c) t += hid[c] * Wc2[c * 2 + tid];
    out[g * 2 + tid] = t;
  }
}

extern "C" void kernel_launch(void* const* d_in, const int* in_sizes, int n_in,
                              void* d_out, int out_size, void* d_ws, size_t ws_size,
                              hipStream_t stream){
  const float* x    = (const float*)d_in[0];
  const int*   ei   = (const int*)d_in[1];
  const int*   batch= (const int*)d_in[2];
  const float* W1   = (const float*)d_in[3];
  const float* as1  = (const float*)d_in[4];
  const float* ad1  = (const float*)d_in[5];
  const float* b1   = (const float*)d_in[6];
  const float* W2   = (const float*)d_in[7];
  const float* as2  = (const float*)d_in[8];
  const float* ad2  = (const float*)d_in[9];
  const float* b2   = (const float*)d_in[10];
  const float* Wg   = (const float*)d_in[11];
  const float* bg   = (const float*)d_in[12];
  const float* Wc1  = (const float*)d_in[13];
  const float* bc1  = (const float*)d_in[14];
  const float* Wc2  = (const float*)d_in[15];
  const float* bc2  = (const float*)d_in[16];

  char* ws = (char*)d_ws;
  unsigned short* x2s   = (unsigned short*)(ws + 0LL);         // [N][512] bf16 split
  unsigned short* out1s = (unsigned short*)(ws + 0LL);         // same region (x2 dead after gemm1)
  __half* h1h   = (__half*)(ws + 51200000LL);   // [N][256] fp16 = 25.6MB
  __half* t2h   = (__half*)(ws + 102400000LL);  // [N][64] fp16 = 6.4MB
  float* hf     = (float*)(ws + 115200000LL);   // 12.8MB (written late by k_agg2w)
  float* P      = (float*)(ws + 115200000LL);   // 8KB (dead before hf written)
  unsigned short* W1B3t = (unsigned short*)(ws + 115208192LL); // 393216B
  unsigned short* W2B3t = (unsigned short*)(ws + 115601408LL); // 98304B
  float* asrc1  = (float*)(ws + 128000000LL);   // 800KB
  float* adst1  = (float*)(ws + 128800000LL);   // 800KB
  float* asrc2  = (float*)(ws + 129600000LL);   // 200KB
  float* adst2  = (float*)(ws + 129800000LL);   // 200KB
  float* attg   = (float*)(ws + 130000000LL);   // 200KB
  int*   deg    = (int*)  (ws + 130200000LL);   // 200KB
  int*   fill   = (int*)  (ws + 130400000LL);   // 200KB
  int*   row_st = (int*)  (ws + 130600256LL);   // 200KB
  int*   col    = (int*)  (ws + 130800256LL);   // 3.4MB
  float* outf   = (float*)d_out;

  hipMemsetAsync(ws + 130200000LL, 0, 400256, stream);

  k_count<<<(M_EDGES + 255) / 256, 256, 0, stream>>>(ei, deg);
  k_scan<<<1, 1024, 0, stream>>>(deg, row_st);
  k_fill<<<(M_EDGES + 255) / 256, 256, 0, stream>>>(ei, row_st, fill, col);

  k_prep<<<321, 768, 0, stream>>>(W1, W2, as1, ad1, W1B3t, W2B3t, P);
  k_att1p<<<N_NODES / 4, 256, 0, stream>>>(x, P, asrc1, adst1, x2s);

  mfma_gemm<128, 1><<<dim3(2, 391), 256, 0, stream>>>(x2s, W1B3t, (void*)h1h, N_NODES, 256);
  k_agg1w<<<N_NODES / 4, 256, 0, stream>>>(h1h, col, row_st, deg, asrc1, adst1, b1, out1s);

  mfma_gemm<64, 1><<<dim3(1, 391), 256, 0, stream>>>(out1s, W2B3t, (void*)t2h, N_NODES, 64);
  k_att2<<<N_NODES / 4, 256, 0, stream>>>(t2h, as2, ad2, asrc2, adst2);
  k_agg2w<<<N_NODES / 4, 256, 0, stream>>>(t2h, col, row_st, deg, asrc2, adst2, b2, Wg, bg, hf, attg);

  k_pool<<<NGRAPH, 256, 0, stream>>>(hf, attg, batch, Wc1, bc1, Wc2, bc2, outf);
}